// Round 3
// baseline (8099.204 us; speedup 1.0000x reference)
//
#include <hip/hip_runtime.h>
#include <hip/hip_bf16.h>
#include <math.h>

using bf16 = __hip_bfloat16;
typedef __attribute__((ext_vector_type(8))) short short8;
typedef __attribute__((ext_vector_type(4))) float floatx4;

#define NB   32      // batch
#define NK   32      // protein slots
#define NNODE 2048   // nodes per graph
#define NEDGE 16384  // edges per graph
#define ND   768     // hidden dim
#define NHH  12      // heads
#define DHH  64      // head dim
#define NFF  3072    // ff dim
#define NG   64      // graphs = 2*NK
#define LTR  4
#define GC   8       // graphs per GNN chunk

static __device__ __forceinline__ float b2f(bf16 x) { return __bfloat162float(x); }
static __device__ __forceinline__ bf16 f2b(float x) { return __float2bfloat16(x); }

// dtype-flexible external load: flag!=0 -> fp32 storage, else bf16 storage
static __device__ __forceinline__ float ldf(const void* p, size_t i, bool f32) {
    return f32 ? ((const float*)p)[i] : b2f(((const bf16*)p)[i]);
}

// ---------------- dtype detection ----------------
// emb_ln_scale is all ones: fp32 word0 = 0x3F800000, bf16-pair word0 = 0x3F803F80
__global__ void detect_dtype_kernel(const void* __restrict__ eln_s, int* __restrict__ flag) {
    if (threadIdx.x == 0 && blockIdx.x == 0) {
        unsigned w = ((const unsigned*)eln_s)[0];
        flag[0] = (w == 0x3F800000u) ? 1 : 0;
    }
}

// ---------------- CSR build ----------------
__global__ __launch_bounds__(256) void count_deg_kernel(const int* __restrict__ edge0,
                                                        const int* __restrict__ edge1,
                                                        int* __restrict__ deg) {
    int gid = blockIdx.x;            // 64 graphs * 64 chunks
    int g = gid >> 6, chunk = gid & 63;
    const int* ep = (g < NK) ? (edge0 + (size_t)g * 2 * NEDGE)
                             : (edge1 + (size_t)(g - NK) * 2 * NEDGE);
    int e = chunk * 256 + threadIdx.x;
    int dst = ep[NEDGE + e];
    atomicAdd(&deg[g * NNODE + dst], 1);
}

__global__ __launch_bounds__(256) void scan_deg_kernel(int* __restrict__ deg,
                                                       int* __restrict__ indptr) {
    int g = blockIdx.x, t = threadIdx.x;
    __shared__ int sums[256];
    int loc[8]; int s = 0;
    #pragma unroll
    for (int i = 0; i < 8; ++i) { loc[i] = deg[g * NNODE + t * 8 + i]; s += loc[i]; }
    sums[t] = s; __syncthreads();
    for (int off = 1; off < 256; off <<= 1) {
        int v = (t >= off) ? sums[t - off] : 0;
        __syncthreads();
        sums[t] += v;
        __syncthreads();
    }
    int run = sums[t] - s;           // exclusive prefix
    #pragma unroll
    for (int i = 0; i < 8; ++i) {
        indptr[g * (NNODE + 1) + t * 8 + i] = run;
        deg[g * NNODE + t * 8 + i] = run;   // becomes cursor
        run += loc[i];
    }
    if (t == 255) indptr[g * (NNODE + 1) + NNODE] = run;
}

__global__ __launch_bounds__(256) void fill_csr_kernel(const int* __restrict__ edge0,
                                                       const int* __restrict__ edge1,
                                                       int* __restrict__ cursor,
                                                       int* __restrict__ csr_src) {
    int gid = blockIdx.x;
    int g = gid >> 6, chunk = gid & 63;
    const int* ep = (g < NK) ? (edge0 + (size_t)g * 2 * NEDGE)
                             : (edge1 + (size_t)(g - NK) * 2 * NEDGE);
    int e = chunk * 256 + threadIdx.x;
    int src = ep[e];
    int dst = ep[NEDGE + e];
    int p = atomicAdd(&cursor[g * NNODE + dst], 1);
    csr_src[(size_t)g * NEDGE + p] = src;
}

// ---------------- GNN ----------------
__global__ __launch_bounds__(256) void gather_embed_kernel(const int* __restrict__ x0,
                                                           const int* __restrict__ x1,
                                                           const void* __restrict__ emb,
                                                           bf16* __restrict__ hC, int g0,
                                                           const int* __restrict__ flag) {
    bool f32 = flag[0] != 0;
    int gn = blockIdx.x;             // gl*2048 + n
    int gl = gn >> 11, n = gn & 2047;
    int g = g0 + gl;
    int id = (g < NK) ? x0[g * NNODE + n] : x1[(g - NK) * NNODE + n];
    bf16* dst = hC + (size_t)gn * ND;
    for (int d = threadIdx.x; d < ND; d += 256)
        dst[d] = f2b(ldf(emb, (size_t)id * ND + d, f32));
}

// x_out[n] = h[n] + sum_{e in CSR(n)} h[src_e]
__global__ __launch_bounds__(256) void gnn_aggregate_kernel(const bf16* __restrict__ hC,
                                                            const int* __restrict__ indptr,
                                                            const int* __restrict__ csr_src,
                                                            bf16* __restrict__ xC, int g0) {
    int gn = blockIdx.x;
    int gl = gn >> 11, n = gn & 2047;
    int g = g0 + gl;
    int beg = indptr[g * (NNODE + 1) + n];
    int end = indptr[g * (NNODE + 1) + n + 1];
    const bf16* hg = hC + (size_t)gl * NNODE * ND;
    const int* cs = csr_src + (size_t)g * NEDGE;
    int t = threadIdx.x;
    float acc[3];
    #pragma unroll
    for (int e2 = 0; e2 < 3; ++e2) acc[e2] = b2f(hg[(size_t)n * ND + t + e2 * 256]);
    for (int e = beg; e < end; ++e) {
        int s = cs[e];
        #pragma unroll
        for (int e2 = 0; e2 < 3; ++e2) acc[e2] += b2f(hg[(size_t)s * ND + t + e2 * 256]);
    }
    #pragma unroll
    for (int e2 = 0; e2 < 3; ++e2) xC[(size_t)gn * ND + t + e2 * 256] = f2b(acc[e2]);
}

__global__ __launch_bounds__(256) void readout_kernel(const bf16* __restrict__ hC,
                                                      const int* __restrict__ batch0,
                                                      const int* __restrict__ batch1,
                                                      float* __restrict__ pooled, int g0) {
    int gl = blockIdx.y;
    int g = g0 + gl;
    int d = blockIdx.x * 256 + threadIdx.x;
    const int* bp = (g < NK) ? (batch0 + (size_t)g * NNODE)
                             : (batch1 + (size_t)(g - NK) * NNODE);
    __shared__ int sb[NNODE];
    for (int i = threadIdx.x; i < NNODE; i += 256) sb[i] = bp[i];
    __syncthreads();
    float acc = 0.f;
    int cur = sb[0];
    for (int n = 0; n < NNODE; ++n) {
        int bn = sb[n];
        if (bn != cur) {
            pooled[((size_t)g * NB + cur) * ND + d] = acc;
            acc = 0.f; cur = bn;
        }
        acc += b2f(hC[((size_t)gl * NNODE + n) * ND + d]);
    }
    pooled[((size_t)g * NB + cur) * ND + d] = acc;
}

__global__ __launch_bounds__(256) void count_nodes_kernel(const int* __restrict__ batch0,
                                                          const int* __restrict__ batch1,
                                                          float* __restrict__ cnt) {
    int g = blockIdx.x, t = threadIdx.x;
    __shared__ int c[NB];
    if (t < NB) c[t] = 0;
    __syncthreads();
    const int* bp = (g < NK) ? (batch0 + (size_t)g * NNODE)
                             : (batch1 + (size_t)(g - NK) * NNODE);
    for (int n = t; n < NNODE; n += 256) atomicAdd(&c[bp[n]], 1);
    __syncthreads();
    if (t < NB) cnt[g * NB + t] = (float)max(c[t], 1);
}

// ---------------- GEMM (bf16 MFMA 16x16x32, 128x128 tile, 4 waves) ----------------
// C[M][N] = act(A[M][K] @ W[K][N] + bias[N]); A is always internal bf16.
// W/bias are external: dtype selected by flag. act: 0=none 1=relu 2=gelu
__global__ __launch_bounds__(256) void gemm_bias_act(const bf16* __restrict__ A,
                                                     const void* __restrict__ Wp,
                                                     const void* __restrict__ biasp,
                                                     void* __restrict__ C,
                                                     unsigned long long wOff,
                                                     unsigned long long bOff,
                                                     int M, int K, int N,
                                                     int act, int outF32,
                                                     const int* __restrict__ flag) {
    bool f32 = flag[0] != 0;
    __shared__ bf16 lA[128][32];     // [row][k]
    __shared__ bf16 lB[128][32];     // [n][k]  (transposed tile of W)
    int nTilesN = N >> 7;
    int bcol = blockIdx.x % nTilesN;
    int brow = blockIdx.x / nTilesN;
    int t = threadIdx.x;
    int wave = t >> 6, lane = t & 63;
    int wr = wave >> 1, wc = wave & 1;
    int l15 = lane & 15, quad = lane >> 4;
    const int row0 = brow << 7, col0 = bcol << 7;

    floatx4 acc[4][4] = {};

    for (int k0 = 0; k0 < K; k0 += 32) {
        // stage A tile (bf16 always)
        {
            int r = t >> 1, ko = (t & 1) * 16;
            const uint4* s4 = reinterpret_cast<const uint4*>(A + (size_t)(row0 + r) * K + k0 + ko);
            uint4 v0 = s4[0], v1 = s4[1];
            *reinterpret_cast<uint4*>(&lA[r][ko])     = v0;
            *reinterpret_cast<uint4*>(&lA[r][ko + 8]) = v1;
        }
        // stage W tile transposed: thread -> (kk = t>>3, no = (t&7)*16)
        {
            int kk = t >> 3, no = (t & 7) * 16;
            if (!f32) {
                const bf16* W = (const bf16*)Wp + wOff;
                const uint4* s4 = reinterpret_cast<const uint4*>(W + (size_t)(k0 + kk) * N + col0 + no);
                uint4 v0 = s4[0], v1 = s4[1];
                const bf16* tp0 = reinterpret_cast<const bf16*>(&v0);
                const bf16* tp1 = reinterpret_cast<const bf16*>(&v1);
                #pragma unroll
                for (int i = 0; i < 8; ++i) lB[no + i][kk] = tp0[i];
                #pragma unroll
                for (int i = 0; i < 8; ++i) lB[no + 8 + i][kk] = tp1[i];
            } else {
                const float* W = (const float*)Wp + wOff;
                const float4* s4 = reinterpret_cast<const float4*>(W + (size_t)(k0 + kk) * N + col0 + no);
                float4 a0 = s4[0], a1 = s4[1], a2 = s4[2], a3 = s4[3];
                lB[no +  0][kk] = f2b(a0.x); lB[no +  1][kk] = f2b(a0.y);
                lB[no +  2][kk] = f2b(a0.z); lB[no +  3][kk] = f2b(a0.w);
                lB[no +  4][kk] = f2b(a1.x); lB[no +  5][kk] = f2b(a1.y);
                lB[no +  6][kk] = f2b(a1.z); lB[no +  7][kk] = f2b(a1.w);
                lB[no +  8][kk] = f2b(a2.x); lB[no +  9][kk] = f2b(a2.y);
                lB[no + 10][kk] = f2b(a2.z); lB[no + 11][kk] = f2b(a2.w);
                lB[no + 12][kk] = f2b(a3.x); lB[no + 13][kk] = f2b(a3.y);
                lB[no + 14][kk] = f2b(a3.z); lB[no + 15][kk] = f2b(a3.w);
            }
        }
        __syncthreads();
        short8 afr[4], bfr[4];
        #pragma unroll
        for (int i = 0; i < 4; ++i)
            afr[i] = *reinterpret_cast<const short8*>(&lA[wr * 64 + i * 16 + l15][quad * 8]);
        #pragma unroll
        for (int j = 0; j < 4; ++j)
            bfr[j] = *reinterpret_cast<const short8*>(&lB[wc * 64 + j * 16 + l15][quad * 8]);
        #pragma unroll
        for (int i = 0; i < 4; ++i)
            #pragma unroll
            for (int j = 0; j < 4; ++j)
                acc[i][j] = __builtin_amdgcn_mfma_f32_16x16x32_bf16(afr[i], bfr[j], acc[i][j], 0, 0, 0);
        __syncthreads();
    }
    // epilogue: D[row=4*quad+r][col=l15] per 16x16 tile (verified m89/m91 layout)
    #pragma unroll
    for (int i = 0; i < 4; ++i) {
        int rbase = row0 + wr * 64 + i * 16 + quad * 4;
        #pragma unroll
        for (int j = 0; j < 4; ++j) {
            int c = col0 + wc * 64 + j * 16 + l15;
            float bv = ldf(biasp, bOff + c, f32);
            #pragma unroll
            for (int r = 0; r < 4; ++r) {
                float v = acc[i][j][r] + bv;
                if (act == 1) v = fmaxf(v, 0.f);
                else if (act == 2) {
                    float x = v;
                    v = 0.5f * x * (1.f + tanhf(0.7978845608028654f * (x + 0.044715f * x * x * x)));
                }
                size_t idx = (size_t)(rbase + r) * N + c;
                if (outF32) ((float*)C)[idx] = v;
                else        ((bf16*)C)[idx] = f2b(v);
            }
        }
    }
}

// ---------------- LayerNorm helpers ----------------
__device__ __forceinline__ void block_ln_768(float (&x)[3], int t,
                                             const void* __restrict__ s,
                                             const void* __restrict__ b,
                                             size_t sOff, bool f32,
                                             float (&y)[3], float* red) {
    float loc = x[0] + x[1] + x[2];
    red[t] = loc; __syncthreads();
    for (int off = 128; off > 0; off >>= 1) {
        if (t < off) red[t] += red[t + off];
        __syncthreads();
    }
    float mean = red[0] * (1.f / 768.f);
    __syncthreads();
    float vs = 0.f;
    #pragma unroll
    for (int e = 0; e < 3; ++e) { float d = x[e] - mean; vs += d * d; }
    red[t] = vs; __syncthreads();
    for (int off = 128; off > 0; off >>= 1) {
        if (t < off) red[t] += red[t + off];
        __syncthreads();
    }
    float var = red[0] * (1.f / 768.f);
    __syncthreads();
    float inv = rsqrtf(var + 1e-12f);
    #pragma unroll
    for (int e = 0; e < 3; ++e) {
        int d = t + e * 256;
        y[e] = (x[e] - mean) * inv * ldf(s, sOff + d, f32) + ldf(b, sOff + d, f32);
    }
}

__global__ __launch_bounds__(256) void combine_embed_ln_kernel(
    const void* __restrict__ raw, const float* __restrict__ pooled, const float* __restrict__ cnt,
    const int* __restrict__ role_ids, const int* __restrict__ pos_ids, const int* __restrict__ hop_ids,
    const void* __restrict__ role_emb, const void* __restrict__ pos_emb, const void* __restrict__ hop_emb,
    const void* __restrict__ lns, const void* __restrict__ lnb,
    float* __restrict__ hT, bf16* __restrict__ hbf,
    const int* __restrict__ flag) {
    bool f32 = flag[0] != 0;
    __shared__ float red[256];
    int token = blockIdx.x;          // b*NK + k
    int b = token >> 5, k = token & 31;
    int t = threadIdx.x;
    int rid = role_ids[b * NK + k];
    int pid = pos_ids[b * NK + k];
    int hid = hop_ids[b * NK + k];
    float c0 = cnt[k * NB + b];
    float c1 = cnt[(NK + k) * NB + b];
    float x[3], y[3];
    #pragma unroll
    for (int e = 0; e < 3; ++e) {
        int d = t + e * 256;
        float p0 = pooled[((size_t)k * NB + b) * ND + d] / c0;
        float p1 = pooled[((size_t)(NK + k) * NB + b) * ND + d] / c1;
        x[e] = ldf(raw, (size_t)token * ND + d, f32) + p0 + p1
             + ldf(role_emb, (size_t)rid * ND + d, f32)
             + ldf(pos_emb, (size_t)pid * ND + d, f32)
             + ldf(hop_emb, (size_t)hid * ND + d, f32);
    }
    block_ln_768(x, t, lns, lnb, 0, f32, y, red);
    #pragma unroll
    for (int e = 0; e < 3; ++e) {
        int d = t + e * 256;
        hT[(size_t)token * ND + d] = y[e];
        hbf[(size_t)token * ND + d] = f2b(y[e]);
    }
}

// extOut=0: write bf16 to outp (internal). extOut=1: write d_out in detected dtype.
__global__ __launch_bounds__(256) void add_ln_kernel(float* __restrict__ hT,
                                                     const float* __restrict__ addv,
                                                     const void* __restrict__ lns,
                                                     const void* __restrict__ lnb,
                                                     unsigned long long sOff,
                                                     void* __restrict__ outp, int extOut,
                                                     const int* __restrict__ flag) {
    bool f32 = flag[0] != 0;
    __shared__ float red[256];
    int token = blockIdx.x;
    int t = threadIdx.x;
    float x[3], y[3];
    #pragma unroll
    for (int e = 0; e < 3; ++e) {
        int d = t + e * 256;
        x[e] = hT[(size_t)token * ND + d] + addv[(size_t)token * ND + d];
    }
    block_ln_768(x, t, lns, lnb, sOff, f32, y, red);
    #pragma unroll
    for (int e = 0; e < 3; ++e) {
        int d = t + e * 256;
        size_t idx = (size_t)token * ND + d;
        hT[idx] = y[e];
        if (extOut && f32) ((float*)outp)[idx] = y[e];
        else               ((bf16*)outp)[idx] = f2b(y[e]);
    }
}

// ---------------- attention (per (b,head) 32x32) ----------------
__global__ __launch_bounds__(256) void attn_kernel(const bf16* __restrict__ q,
                                                   const bf16* __restrict__ k,
                                                   const bf16* __restrict__ v,
                                                   bf16* __restrict__ ctx) {
    int blk = blockIdx.x;            // b*NHH + h
    int b = blk / NHH, h = blk % NHH;
    __shared__ float lq[NK][DHH], lk[NK][DHH], lv[NK][DHH];
    __shared__ float ls[NK][NK];
    int t = threadIdx.x;
    for (int i = t; i < NK * DHH; i += 256) {
        int tok = i >> 6, d = i & 63;
        size_t idx = ((size_t)(b * NK + tok)) * ND + h * DHH + d;
        lq[tok][d] = b2f(q[idx]);
        lk[tok][d] = b2f(k[idx]);
        lv[tok][d] = b2f(v[idx]);
    }
    __syncthreads();
    const float scale = 0.125f;      // 1/sqrt(64)
    for (int i = t; i < NK * NK; i += 256) {
        int qi = i >> 5, kj = i & 31;
        float s = 0.f;
        #pragma unroll
        for (int d = 0; d < DHH; ++d) s += lq[qi][d] * lk[kj][d];
        ls[qi][kj] = s * scale;
    }
    __syncthreads();
    if (t < NK) {
        float m = -1e30f;
        for (int j = 0; j < NK; ++j) m = fmaxf(m, ls[t][j]);
        float sum = 0.f;
        for (int j = 0; j < NK; ++j) { float e = expf(ls[t][j] - m); ls[t][j] = e; sum += e; }
        float inv = 1.f / sum;
        for (int j = 0; j < NK; ++j) ls[t][j] *= inv;
    }
    __syncthreads();
    for (int i = t; i < NK * DHH; i += 256) {
        int qi = i >> 6, d = i & 63;
        float s = 0.f;
        #pragma unroll
        for (int j = 0; j < NK; ++j) s += ls[qi][j] * lv[j][d];
        ctx[((size_t)(b * NK + qi)) * ND + h * DHH + d] = f2b(s);
    }
}

// ---------------- launch ----------------
extern "C" void kernel_launch(void* const* d_in, const int* in_sizes, int n_in,
                              void* d_out, int out_size, void* d_ws, size_t ws_size,
                              hipStream_t stream) {
    const void* raw      = d_in[0];
    const int*  x0       = (const int*)d_in[1];
    const int*  edge0    = (const int*)d_in[2];
    const int*  batch0   = (const int*)d_in[3];
    const int*  x1       = (const int*)d_in[4];
    const int*  edge1    = (const int*)d_in[5];
    const int*  batch1   = (const int*)d_in[6];
    const int*  role_ids = (const int*)d_in[7];
    const int*  pos_ids  = (const int*)d_in[8];
    const int*  hop_ids  = (const int*)d_in[9];
    const void* amino    = d_in[10];
    const void* gnnW     = d_in[11];
    const void* gnnb     = d_in[12];
    const void* role_emb = d_in[13];
    const void* pos_emb  = d_in[14];
    const void* hop_emb  = d_in[15];
    const void* eln_s    = d_in[16];
    const void* eln_b    = d_in[17];
    const void* Wq       = d_in[18];
    const void* bq       = d_in[19];
    const void* Wk       = d_in[20];
    const void* bk       = d_in[21];
    const void* Wv       = d_in[22];
    const void* bv       = d_in[23];
    const void* Wo       = d_in[24];
    const void* bo       = d_in[25];
    const void* ln1_s    = d_in[26];
    const void* ln1_b    = d_in[27];
    const void* W1       = d_in[28];
    const void* b1       = d_in[29];
    const void* W2       = d_in[30];
    const void* b2       = d_in[31];
    const void* ln2_s    = d_in[32];
    const void* ln2_b    = d_in[33];

    char* ws = (char*)d_ws;
    size_t off = 0;
    auto alloc = [&](size_t bytes) -> void* {
        void* p = ws + off;
        off = (off + bytes + 255) & ~(size_t)255;
        return p;
    };
    int*   dflag   = (int*)alloc(256);
    float* pooled  = (float*)alloc((size_t)NG * NB * ND * 4);          // 6.29 MB
    float* cnt     = (float*)alloc((size_t)NG * NB * 4);
    int*   indptr  = (int*)alloc((size_t)NG * (NNODE + 1) * 4);        // 524 KB
    int*   csr_src = (int*)alloc((size_t)NG * NEDGE * 4);              // 4.19 MB
    int*   degcur  = (int*)alloc((size_t)NG * NNODE * 4);              // 524 KB
    // big region: GNN chunk buffers, later aliased by transformer buffers (~50 MB)
    char* bigbase = (char*)alloc((size_t)GC * NNODE * ND * 2 * 2);
    bf16* hC = (bf16*)bigbase;
    bf16* xC = (bf16*)(bigbase + (size_t)GC * NNODE * ND * 2);
    size_t toff = 0;
    auto talloc = [&](size_t bytes) -> void* {
        void* p = bigbase + toff;
        toff = (toff + bytes + 255) & ~(size_t)255;
        return p;
    };
    float* hT    = (float*)talloc((size_t)NB * NK * ND * 4);
    bf16*  hbf   = (bf16*)talloc((size_t)NB * NK * ND * 2);
    bf16*  qb    = (bf16*)talloc((size_t)NB * NK * ND * 2);
    bf16*  kb    = (bf16*)talloc((size_t)NB * NK * ND * 2);
    bf16*  vb    = (bf16*)talloc((size_t)NB * NK * ND * 2);
    bf16*  ctxb  = (bf16*)talloc((size_t)NB * NK * ND * 2);
    float* resid = (float*)talloc((size_t)NB * NK * ND * 4);
    bf16*  ffbuf = (bf16*)talloc((size_t)NB * NK * NFF * 2);

    auto gemm = [&](const bf16* A, const void* W, const void* bias,
                    unsigned long long wOff, unsigned long long bOff, void* C,
                    int M, int K, int N, int act, int outF32) {
        int blocks = (M >> 7) * (N >> 7);
        gemm_bias_act<<<blocks, 256, 0, stream>>>(A, W, bias, C, wOff, bOff,
                                                  M, K, N, act, outF32, dflag);
    };

    // ---- dtype detection (must precede all external-input readers) ----
    detect_dtype_kernel<<<1, 64, 0, stream>>>(eln_s, dflag);

    // ---- CSR build ----
    hipMemsetAsync(degcur, 0, (size_t)NG * NNODE * 4, stream);
    count_deg_kernel<<<NG * 64, 256, 0, stream>>>(edge0, edge1, degcur);
    scan_deg_kernel<<<NG, 256, 0, stream>>>(degcur, indptr);
    fill_csr_kernel<<<NG * 64, 256, 0, stream>>>(edge0, edge1, degcur, csr_src);

    // ---- GNN, chunked over graphs ----
    hipMemsetAsync(pooled, 0, (size_t)NG * NB * ND * 4, stream);
    for (int g0 = 0; g0 < NG; g0 += GC) {
        gather_embed_kernel<<<GC * NNODE, 256, 0, stream>>>(x0, x1, amino, hC, g0, dflag);
        for (int l = 0; l < 2; ++l) {
            gnn_aggregate_kernel<<<GC * NNODE, 256, 0, stream>>>(hC, indptr, csr_src, xC, g0);
            gemm(xC, gnnW, gnnb, (size_t)l * ND * ND, (size_t)l * ND, hC,
                 GC * NNODE, ND, ND, /*relu*/1, /*outF32*/0);
        }
        dim3 grid(ND / 256, GC);
        readout_kernel<<<grid, 256, 0, stream>>>(hC, batch0, batch1, pooled, g0);
    }
    count_nodes_kernel<<<NG, 256, 0, stream>>>(batch0, batch1, cnt);

    // ---- embeddings + LN ----
    combine_embed_ln_kernel<<<NB * NK, 256, 0, stream>>>(
        raw, pooled, cnt, role_ids, pos_ids, hop_ids,
        role_emb, pos_emb, hop_emb, eln_s, eln_b, hT, hbf, dflag);

    // ---- transformer ----
    const int M = NB * NK;
    for (int l = 0; l < LTR; ++l) {
        unsigned long long wo = (unsigned long long)l * ND * ND;
        unsigned long long bo_ = (unsigned long long)l * ND;
        gemm(hbf, Wq, bq, wo, bo_, qb, M, ND, ND, 0, 0);
        gemm(hbf, Wk, bk, wo, bo_, kb, M, ND, ND, 0, 0);
        gemm(hbf, Wv, bv, wo, bo_, vb, M, ND, ND, 0, 0);
        attn_kernel<<<NB * NHH, 256, 0, stream>>>(qb, kb, vb, ctxb);
        gemm(ctxb, Wo, bo, wo, bo_, resid, M, ND, ND, 0, /*outF32*/1);
        add_ln_kernel<<<M, 256, 0, stream>>>(hT, resid, ln1_s, ln1_b, bo_, hbf, 0, dflag);
        gemm(hbf, W1, b1, (unsigned long long)l * ND * NFF, (unsigned long long)l * NFF,
             ffbuf, M, ND, NFF, /*gelu*/2, 0);
        gemm(ffbuf, W2, b2, (unsigned long long)l * NFF * ND, bo_,
             resid, M, NFF, ND, 0, /*outF32*/1);
        int ext = (l == LTR - 1) ? 1 : 0;
        void* outb = ext ? d_out : (void*)hbf;
        add_ln_kernel<<<M, 256, 0, stream>>>(hT, resid, ln2_s, ln2_b, bo_, outb, ext, dflag);
    }
}

// Round 4
// 3838.646 us; speedup vs baseline: 2.1099x; 2.1099x over previous
//
#include <hip/hip_runtime.h>
#include <hip/hip_bf16.h>
#include <math.h>

using bf16 = __hip_bfloat16;
typedef __attribute__((ext_vector_type(8))) short short8;
typedef __attribute__((ext_vector_type(4))) float floatx4;

#define NB   32      // batch
#define NK   32      // protein slots
#define NNODE 2048   // nodes per graph
#define NEDGE 16384  // edges per graph
#define ND   768     // hidden dim
#define NHH  12      // heads
#define DHH  64      // head dim
#define NFF  3072    // ff dim
#define NG   64      // graphs = 2*NK
#define LTR  4
#define GC   8       // graphs per GNN chunk

static __device__ __forceinline__ float b2f(bf16 x) { return __bfloat162float(x); }
static __device__ __forceinline__ bf16 f2b(float x) { return __float2bfloat16(x); }

// dtype-flexible external load: f32 -> fp32 storage, else bf16 storage
static __device__ __forceinline__ float ldf(const void* p, size_t i, bool f32) {
    return f32 ? ((const float*)p)[i] : b2f(((const bf16*)p)[i]);
}

// ---------------- dtype detection ----------------
// emb_ln_scale is all ones: fp32 word0 = 0x3F800000, bf16-pair word0 = 0x3F803F80
__global__ void detect_dtype_kernel(const void* __restrict__ eln_s, int* __restrict__ flag) {
    if (threadIdx.x == 0 && blockIdx.x == 0) {
        unsigned w = ((const unsigned*)eln_s)[0];
        flag[0] = (w == 0x3F800000u) ? 1 : 0;
    }
}

// ---------------- CSR build ----------------
__global__ __launch_bounds__(256) void count_deg_kernel(const int* __restrict__ edge0,
                                                        const int* __restrict__ edge1,
                                                        int* __restrict__ deg) {
    int gid = blockIdx.x;            // 64 graphs * 64 chunks
    int g = gid >> 6, chunk = gid & 63;
    const int* ep = (g < NK) ? (edge0 + (size_t)g * 2 * NEDGE)
                             : (edge1 + (size_t)(g - NK) * 2 * NEDGE);
    int e = chunk * 256 + threadIdx.x;
    int dst = ep[NEDGE + e];
    atomicAdd(&deg[g * NNODE + dst], 1);
}

__global__ __launch_bounds__(256) void scan_deg_kernel(int* __restrict__ deg,
                                                       int* __restrict__ indptr) {
    int g = blockIdx.x, t = threadIdx.x;
    __shared__ int sums[256];
    int loc[8]; int s = 0;
    #pragma unroll
    for (int i = 0; i < 8; ++i) { loc[i] = deg[g * NNODE + t * 8 + i]; s += loc[i]; }
    sums[t] = s; __syncthreads();
    for (int off = 1; off < 256; off <<= 1) {
        int v = (t >= off) ? sums[t - off] : 0;
        __syncthreads();
        sums[t] += v;
        __syncthreads();
    }
    int run = sums[t] - s;           // exclusive prefix
    #pragma unroll
    for (int i = 0; i < 8; ++i) {
        indptr[g * (NNODE + 1) + t * 8 + i] = run;
        deg[g * NNODE + t * 8 + i] = run;   // becomes cursor
        run += loc[i];
    }
    if (t == 255) indptr[g * (NNODE + 1) + NNODE] = run;
}

__global__ __launch_bounds__(256) void fill_csr_kernel(const int* __restrict__ edge0,
                                                       const int* __restrict__ edge1,
                                                       int* __restrict__ cursor,
                                                       int* __restrict__ csr_src) {
    int gid = blockIdx.x;
    int g = gid >> 6, chunk = gid & 63;
    const int* ep = (g < NK) ? (edge0 + (size_t)g * 2 * NEDGE)
                             : (edge1 + (size_t)(g - NK) * 2 * NEDGE);
    int e = chunk * 256 + threadIdx.x;
    int src = ep[e];
    int dst = ep[NEDGE + e];
    int p = atomicAdd(&cursor[g * NNODE + dst], 1);
    csr_src[(size_t)g * NEDGE + p] = src;
}

// ---------------- GNN ----------------
__global__ __launch_bounds__(256) void gather_embed_kernel(const int* __restrict__ x0,
                                                           const int* __restrict__ x1,
                                                           const void* __restrict__ emb,
                                                           bf16* __restrict__ hC, int g0,
                                                           const int* __restrict__ flag) {
    bool f32 = flag[0] != 0;
    int gn = blockIdx.x;             // gl*2048 + n
    int gl = gn >> 11, n = gn & 2047;
    int g = g0 + gl;
    int id = (g < NK) ? x0[g * NNODE + n] : x1[(g - NK) * NNODE + n];
    bf16* dst = hC + (size_t)gn * ND;
    for (int d = threadIdx.x; d < ND; d += 256)
        dst[d] = f2b(ldf(emb, (size_t)id * ND + d, f32));
}

// x_out[n] = h[n] + sum_{e in CSR(n)} h[src_e]
__global__ __launch_bounds__(256) void gnn_aggregate_kernel(const bf16* __restrict__ hC,
                                                            const int* __restrict__ indptr,
                                                            const int* __restrict__ csr_src,
                                                            bf16* __restrict__ xC, int g0) {
    int gn = blockIdx.x;
    int gl = gn >> 11, n = gn & 2047;
    int g = g0 + gl;
    int beg = indptr[g * (NNODE + 1) + n];
    int end = indptr[g * (NNODE + 1) + n + 1];
    const bf16* hg = hC + (size_t)gl * NNODE * ND;
    const int* cs = csr_src + (size_t)g * NEDGE;
    int t = threadIdx.x;
    float acc[3];
    #pragma unroll
    for (int e2 = 0; e2 < 3; ++e2) acc[e2] = b2f(hg[(size_t)n * ND + t + e2 * 256]);
    for (int e = beg; e < end; ++e) {
        int s = cs[e];
        #pragma unroll
        for (int e2 = 0; e2 < 3; ++e2) acc[e2] += b2f(hg[(size_t)s * ND + t + e2 * 256]);
    }
    #pragma unroll
    for (int e2 = 0; e2 < 3; ++e2) xC[(size_t)gn * ND + t + e2 * 256] = f2b(acc[e2]);
}

// one block per (graph-in-chunk, batch-value); sorted batch -> binary-search range;
// writes MEAN directly (sum / max(len,1))
__global__ __launch_bounds__(256) void readout_kernel(const bf16* __restrict__ hC,
                                                      const int* __restrict__ batch0,
                                                      const int* __restrict__ batch1,
                                                      float* __restrict__ pooled, int g0) {
    int gl = blockIdx.y;
    int g = g0 + gl;
    int b = blockIdx.x;              // batch value [0,NB)
    const int* bp = (g < NK) ? (batch0 + (size_t)g * NNODE)
                             : (batch1 + (size_t)(g - NK) * NNODE);
    // lower_bound(b) and lower_bound(b+1), wave-uniform
    int lo = 0, hi = NNODE;
    while (lo < hi) { int mid = (lo + hi) >> 1; if (bp[mid] < b) lo = mid + 1; else hi = mid; }
    int start = lo;
    hi = NNODE;
    while (lo < hi) { int mid = (lo + hi) >> 1; if (bp[mid] < b + 1) lo = mid + 1; else hi = mid; }
    int end = lo;
    int t = threadIdx.x;
    float acc[3] = {0.f, 0.f, 0.f};
    const bf16* hg = hC + (size_t)gl * NNODE * ND;
    for (int n = start; n < end; ++n) {
        #pragma unroll
        for (int e = 0; e < 3; ++e)
            acc[e] += b2f(hg[(size_t)n * ND + t + e * 256]);
    }
    float inv = 1.f / (float)max(end - start, 1);
    #pragma unroll
    for (int e = 0; e < 3; ++e)
        pooled[((size_t)g * NB + b) * ND + t + e * 256] = acc[e] * inv;
}

// ---------------- GEMM (bf16 MFMA 16x16x32, 128x128 tile, 4 waves) ----------------
// C[M][N] = act(A[M][K] @ W[K][N] + bias[N]); A is always internal bf16.
// W/bias external: dtype by flag. act: 0=none 1=relu 2=gelu
__global__ __launch_bounds__(256) void gemm_bias_act(const bf16* __restrict__ A,
                                                     const void* __restrict__ Wp,
                                                     const void* __restrict__ biasp,
                                                     void* __restrict__ C,
                                                     unsigned long long wOff,
                                                     unsigned long long bOff,
                                                     int M, int K, int N,
                                                     int act, int outF32,
                                                     const int* __restrict__ flag) {
    bool f32 = flag[0] != 0;
    __shared__ bf16 lA[128][32];     // [row][k]
    __shared__ bf16 lB[128][32];     // [n][k]  (transposed tile of W)
    int nTilesN = N >> 7;
    int bcol = blockIdx.x % nTilesN;
    int brow = blockIdx.x / nTilesN;
    int t = threadIdx.x;
    int wave = t >> 6, lane = t & 63;
    int wr = wave >> 1, wc = wave & 1;
    int l15 = lane & 15, quad = lane >> 4;
    const int row0 = brow << 7, col0 = bcol << 7;

    floatx4 acc[4][4] = {};

    for (int k0 = 0; k0 < K; k0 += 32) {
        {
            int r = t >> 1, ko = (t & 1) * 16;
            const uint4* s4 = reinterpret_cast<const uint4*>(A + (size_t)(row0 + r) * K + k0 + ko);
            uint4 v0 = s4[0], v1 = s4[1];
            *reinterpret_cast<uint4*>(&lA[r][ko])     = v0;
            *reinterpret_cast<uint4*>(&lA[r][ko + 8]) = v1;
        }
        {
            int kk = t >> 3, no = (t & 7) * 16;
            if (!f32) {
                const bf16* W = (const bf16*)Wp + wOff;
                const uint4* s4 = reinterpret_cast<const uint4*>(W + (size_t)(k0 + kk) * N + col0 + no);
                uint4 v0 = s4[0], v1 = s4[1];
                const bf16* tp0 = reinterpret_cast<const bf16*>(&v0);
                const bf16* tp1 = reinterpret_cast<const bf16*>(&v1);
                #pragma unroll
                for (int i = 0; i < 8; ++i) lB[no + i][kk] = tp0[i];
                #pragma unroll
                for (int i = 0; i < 8; ++i) lB[no + 8 + i][kk] = tp1[i];
            } else {
                const float* W = (const float*)Wp + wOff;
                const float4* s4 = reinterpret_cast<const float4*>(W + (size_t)(k0 + kk) * N + col0 + no);
                float4 a0 = s4[0], a1 = s4[1], a2 = s4[2], a3 = s4[3];
                lB[no +  0][kk] = f2b(a0.x); lB[no +  1][kk] = f2b(a0.y);
                lB[no +  2][kk] = f2b(a0.z); lB[no +  3][kk] = f2b(a0.w);
                lB[no +  4][kk] = f2b(a1.x); lB[no +  5][kk] = f2b(a1.y);
                lB[no +  6][kk] = f2b(a1.z); lB[no +  7][kk] = f2b(a1.w);
                lB[no +  8][kk] = f2b(a2.x); lB[no +  9][kk] = f2b(a2.y);
                lB[no + 10][kk] = f2b(a2.z); lB[no + 11][kk] = f2b(a2.w);
                lB[no + 12][kk] = f2b(a3.x); lB[no + 13][kk] = f2b(a3.y);
                lB[no + 14][kk] = f2b(a3.z); lB[no + 15][kk] = f2b(a3.w);
            }
        }
        __syncthreads();
        short8 afr[4], bfr[4];
        #pragma unroll
        for (int i = 0; i < 4; ++i)
            afr[i] = *reinterpret_cast<const short8*>(&lA[wr * 64 + i * 16 + l15][quad * 8]);
        #pragma unroll
        for (int j = 0; j < 4; ++j)
            bfr[j] = *reinterpret_cast<const short8*>(&lB[wc * 64 + j * 16 + l15][quad * 8]);
        #pragma unroll
        for (int i = 0; i < 4; ++i)
            #pragma unroll
            for (int j = 0; j < 4; ++j)
                acc[i][j] = __builtin_amdgcn_mfma_f32_16x16x32_bf16(afr[i], bfr[j], acc[i][j], 0, 0, 0);
        __syncthreads();
    }
    #pragma unroll
    for (int i = 0; i < 4; ++i) {
        int rbase = row0 + wr * 64 + i * 16 + quad * 4;
        #pragma unroll
        for (int j = 0; j < 4; ++j) {
            int c = col0 + wc * 64 + j * 16 + l15;
            float bv = ldf(biasp, bOff + c, f32);
            #pragma unroll
            for (int r = 0; r < 4; ++r) {
                float v = acc[i][j][r] + bv;
                if (act == 1) v = fmaxf(v, 0.f);
                else if (act == 2) {
                    float x = v;
                    v = 0.5f * x * (1.f + tanhf(0.7978845608028654f * (x + 0.044715f * x * x * x)));
                }
                size_t idx = (size_t)(rbase + r) * N + c;
                if (outF32) ((float*)C)[idx] = v;
                else        ((bf16*)C)[idx] = f2b(v);
            }
        }
    }
}

// ---------------- LayerNorm helpers ----------------
__device__ __forceinline__ void block_ln_768(float (&x)[3], int t,
                                             const void* __restrict__ s,
                                             const void* __restrict__ b,
                                             size_t sOff, bool f32,
                                             float (&y)[3], float* red) {
    float loc = x[0] + x[1] + x[2];
    red[t] = loc; __syncthreads();
    for (int off = 128; off > 0; off >>= 1) {
        if (t < off) red[t] += red[t + off];
        __syncthreads();
    }
    float mean = red[0] * (1.f / 768.f);
    __syncthreads();
    float vs = 0.f;
    #pragma unroll
    for (int e = 0; e < 3; ++e) { float d = x[e] - mean; vs += d * d; }
    red[t] = vs; __syncthreads();
    for (int off = 128; off > 0; off >>= 1) {
        if (t < off) red[t] += red[t + off];
        __syncthreads();
    }
    float var = red[0] * (1.f / 768.f);
    __syncthreads();
    float inv = rsqrtf(var + 1e-12f);
    #pragma unroll
    for (int e = 0; e < 3; ++e) {
        int d = t + e * 256;
        y[e] = (x[e] - mean) * inv * ldf(s, sOff + d, f32) + ldf(b, sOff + d, f32);
    }
}

__global__ __launch_bounds__(256) void combine_embed_ln_kernel(
    const void* __restrict__ raw, const float* __restrict__ pooled,
    const int* __restrict__ role_ids, const int* __restrict__ pos_ids, const int* __restrict__ hop_ids,
    const void* __restrict__ role_emb, const void* __restrict__ pos_emb, const void* __restrict__ hop_emb,
    const void* __restrict__ lns, const void* __restrict__ lnb,
    float* __restrict__ hT, bf16* __restrict__ hbf,
    const int* __restrict__ flag) {
    bool f32 = flag[0] != 0;
    __shared__ float red[256];
    int token = blockIdx.x;          // b*NK + k
    int b = token >> 5, k = token & 31;
    int t = threadIdx.x;
    int rid = role_ids[b * NK + k];
    int pid = pos_ids[b * NK + k];
    int hid = hop_ids[b * NK + k];
    float x[3], y[3];
    #pragma unroll
    for (int e = 0; e < 3; ++e) {
        int d = t + e * 256;
        float p0 = pooled[((size_t)k * NB + b) * ND + d];
        float p1 = pooled[((size_t)(NK + k) * NB + b) * ND + d];
        x[e] = ldf(raw, (size_t)token * ND + d, f32) + p0 + p1
             + ldf(role_emb, (size_t)rid * ND + d, f32)
             + ldf(pos_emb, (size_t)pid * ND + d, f32)
             + ldf(hop_emb, (size_t)hid * ND + d, f32);
    }
    block_ln_768(x, t, lns, lnb, 0, f32, y, red);
    #pragma unroll
    for (int e = 0; e < 3; ++e) {
        int d = t + e * 256;
        hT[(size_t)token * ND + d] = y[e];
        hbf[(size_t)token * ND + d] = f2b(y[e]);
    }
}

// extOut=0: write bf16 to outp (internal). extOut=1: write d_out in detected dtype.
__global__ __launch_bounds__(256) void add_ln_kernel(float* __restrict__ hT,
                                                     const float* __restrict__ addv,
                                                     const void* __restrict__ lns,
                                                     const void* __restrict__ lnb,
                                                     unsigned long long sOff,
                                                     void* __restrict__ outp, int extOut,
                                                     const int* __restrict__ flag) {
    bool f32 = flag[0] != 0;
    __shared__ float red[256];
    int token = blockIdx.x;
    int t = threadIdx.x;
    float x[3], y[3];
    #pragma unroll
    for (int e = 0; e < 3; ++e) {
        int d = t + e * 256;
        x[e] = hT[(size_t)token * ND + d] + addv[(size_t)token * ND + d];
    }
    block_ln_768(x, t, lns, lnb, sOff, f32, y, red);
    #pragma unroll
    for (int e = 0; e < 3; ++e) {
        int d = t + e * 256;
        size_t idx = (size_t)token * ND + d;
        hT[idx] = y[e];
        if (extOut && f32) ((float*)outp)[idx] = y[e];
        else               ((bf16*)outp)[idx] = f2b(y[e]);
    }
}

// ---------------- attention (per (b,head) 32x32) ----------------
__global__ __launch_bounds__(256) void attn_kernel(const bf16* __restrict__ q,
                                                   const bf16* __restrict__ k,
                                                   const bf16* __restrict__ v,
                                                   bf16* __restrict__ ctx) {
    int blk = blockIdx.x;            // b*NHH + h
    int b = blk / NHH, h = blk % NHH;
    __shared__ float lq[NK][DHH], lk[NK][DHH], lv[NK][DHH];
    __shared__ float ls[NK][NK];
    int t = threadIdx.x;
    for (int i = t; i < NK * DHH; i += 256) {
        int tok = i >> 6, d = i & 63;
        size_t idx = ((size_t)(b * NK + tok)) * ND + h * DHH + d;
        lq[tok][d] = b2f(q[idx]);
        lk[tok][d] = b2f(k[idx]);
        lv[tok][d] = b2f(v[idx]);
    }
    __syncthreads();
    const float scale = 0.125f;      // 1/sqrt(64)
    for (int i = t; i < NK * NK; i += 256) {
        int qi = i >> 5, kj = i & 31;
        float s = 0.f;
        #pragma unroll
        for (int d = 0; d < DHH; ++d) s += lq[qi][d] * lk[kj][d];
        ls[qi][kj] = s * scale;
    }
    __syncthreads();
    if (t < NK) {
        float m = -1e30f;
        for (int j = 0; j < NK; ++j) m = fmaxf(m, ls[t][j]);
        float sum = 0.f;
        for (int j = 0; j < NK; ++j) { float e = expf(ls[t][j] - m); ls[t][j] = e; sum += e; }
        float inv = 1.f / sum;
        for (int j = 0; j < NK; ++j) ls[t][j] *= inv;
    }
    __syncthreads();
    for (int i = t; i < NK * DHH; i += 256) {
        int qi = i >> 6, d = i & 63;
        float s = 0.f;
        #pragma unroll
        for (int j = 0; j < NK; ++j) s += ls[qi][j] * lv[j][d];
        ctx[((size_t)(b * NK + qi)) * ND + h * DHH + d] = f2b(s);
    }
}

// ---------------- launch ----------------
extern "C" void kernel_launch(void* const* d_in, const int* in_sizes, int n_in,
                              void* d_out, int out_size, void* d_ws, size_t ws_size,
                              hipStream_t stream) {
    const void* raw      = d_in[0];
    const int*  x0       = (const int*)d_in[1];
    const int*  edge0    = (const int*)d_in[2];
    const int*  batch0   = (const int*)d_in[3];
    const int*  x1       = (const int*)d_in[4];
    const int*  edge1    = (const int*)d_in[5];
    const int*  batch1   = (const int*)d_in[6];
    const int*  role_ids = (const int*)d_in[7];
    const int*  pos_ids  = (const int*)d_in[8];
    const int*  hop_ids  = (const int*)d_in[9];
    const void* amino    = d_in[10];
    const void* gnnW     = d_in[11];
    const void* gnnb     = d_in[12];
    const void* role_emb = d_in[13];
    const void* pos_emb  = d_in[14];
    const void* hop_emb  = d_in[15];
    const void* eln_s    = d_in[16];
    const void* eln_b    = d_in[17];
    const void* Wq       = d_in[18];
    const void* bq       = d_in[19];
    const void* Wk       = d_in[20];
    const void* bk       = d_in[21];
    const void* Wv       = d_in[22];
    const void* bv       = d_in[23];
    const void* Wo       = d_in[24];
    const void* bo       = d_in[25];
    const void* ln1_s    = d_in[26];
    const void* ln1_b    = d_in[27];
    const void* W1       = d_in[28];
    const void* b1       = d_in[29];
    const void* W2       = d_in[30];
    const void* b2       = d_in[31];
    const void* ln2_s    = d_in[32];
    const void* ln2_b    = d_in[33];

    char* ws = (char*)d_ws;
    size_t off = 0;
    auto alloc = [&](size_t bytes) -> void* {
        void* p = ws + off;
        off = (off + bytes + 255) & ~(size_t)255;
        return p;
    };
    int*   dflag   = (int*)alloc(256);
    float* pooled  = (float*)alloc((size_t)NG * NB * ND * 4);          // 6.29 MB
    int*   indptr  = (int*)alloc((size_t)NG * (NNODE + 1) * 4);        // 524 KB
    int*   csr_src = (int*)alloc((size_t)NG * NEDGE * 4);              // 4.19 MB
    int*   degcur  = (int*)alloc((size_t)NG * NNODE * 4);              // 524 KB
    // big region: GNN chunk buffers, later aliased by transformer buffers (~50 MB)
    char* bigbase = (char*)alloc((size_t)GC * NNODE * ND * 2 * 2);
    bf16* hC = (bf16*)bigbase;
    bf16* xC = (bf16*)(bigbase + (size_t)GC * NNODE * ND * 2);
    size_t toff = 0;
    auto talloc = [&](size_t bytes) -> void* {
        void* p = bigbase + toff;
        toff = (toff + bytes + 255) & ~(size_t)255;
        return p;
    };
    float* hT    = (float*)talloc((size_t)NB * NK * ND * 4);
    bf16*  hbf   = (bf16*)talloc((size_t)NB * NK * ND * 2);
    bf16*  qb    = (bf16*)talloc((size_t)NB * NK * ND * 2);
    bf16*  kb    = (bf16*)talloc((size_t)NB * NK * ND * 2);
    bf16*  vb    = (bf16*)talloc((size_t)NB * NK * ND * 2);
    bf16*  ctxb  = (bf16*)talloc((size_t)NB * NK * ND * 2);
    float* resid = (float*)talloc((size_t)NB * NK * ND * 4);
    bf16*  ffbuf = (bf16*)talloc((size_t)NB * NK * NFF * 2);

    auto gemm = [&](const bf16* A, const void* W, const void* bias,
                    unsigned long long wOff, unsigned long long bOff, void* C,
                    int M, int K, int N, int act, int outF32) {
        int blocks = (M >> 7) * (N >> 7);
        gemm_bias_act<<<blocks, 256, 0, stream>>>(A, W, bias, C, wOff, bOff,
                                                  M, K, N, act, outF32, dflag);
    };

    // ---- dtype detection (must precede all external-input readers) ----
    detect_dtype_kernel<<<1, 64, 0, stream>>>(eln_s, dflag);

    // ---- CSR build ----
    hipMemsetAsync(degcur, 0, (size_t)NG * NNODE * 4, stream);
    count_deg_kernel<<<NG * 64, 256, 0, stream>>>(edge0, edge1, degcur);
    scan_deg_kernel<<<NG, 256, 0, stream>>>(degcur, indptr);
    fill_csr_kernel<<<NG * 64, 256, 0, stream>>>(edge0, edge1, degcur, csr_src);

    // ---- GNN, chunked over graphs ----
    for (int g0 = 0; g0 < NG; g0 += GC) {
        gather_embed_kernel<<<GC * NNODE, 256, 0, stream>>>(x0, x1, amino, hC, g0, dflag);
        for (int l = 0; l < 2; ++l) {
            gnn_aggregate_kernel<<<GC * NNODE, 256, 0, stream>>>(hC, indptr, csr_src, xC, g0);
            gemm(xC, gnnW, gnnb, (size_t)l * ND * ND, (size_t)l * ND, hC,
                 GC * NNODE, ND, ND, /*relu*/1, /*outF32*/0);
        }
        dim3 grid(NB, GC);           // one block per (batch value, graph-in-chunk)
        readout_kernel<<<grid, 256, 0, stream>>>(hC, batch0, batch1, pooled, g0);
    }

    // ---- embeddings + LN ----
    combine_embed_ln_kernel<<<NB * NK, 256, 0, stream>>>(
        raw, pooled, role_ids, pos_ids, hop_ids,
        role_emb, pos_emb, hop_emb, eln_s, eln_b, hT, hbf, dflag);

    // ---- transformer ----
    const int M = NB * NK;
    for (int l = 0; l < LTR; ++l) {
        unsigned long long wo = (unsigned long long)l * ND * ND;
        unsigned long long bo_ = (unsigned long long)l * ND;
        gemm(hbf, Wq, bq, wo, bo_, qb, M, ND, ND, 0, 0);
        gemm(hbf, Wk, bk, wo, bo_, kb, M, ND, ND, 0, 0);
        gemm(hbf, Wv, bv, wo, bo_, vb, M, ND, ND, 0, 0);
        attn_kernel<<<NB * NHH, 256, 0, stream>>>(qb, kb, vb, ctxb);
        gemm(ctxb, Wo, bo, wo, bo_, resid, M, ND, ND, 0, /*outF32*/1);
        add_ln_kernel<<<M, 256, 0, stream>>>(hT, resid, ln1_s, ln1_b, bo_, hbf, 0, dflag);
        gemm(hbf, W1, b1, (unsigned long long)l * ND * NFF, (unsigned long long)l * NFF,
             ffbuf, M, ND, NFF, /*gelu*/2, 0);
        gemm(ffbuf, W2, b2, (unsigned long long)l * NFF * ND, bo_,
             resid, M, NFF, ND, 0, /*outF32*/1);
        int ext = (l == LTR - 1) ? 1 : 0;
        void* outb = ext ? d_out : (void*)hbf;
        add_ln_kernel<<<M, 256, 0, stream>>>(hT, resid, ln2_s, ln2_b, bo_, outb, ext, dflag);
    }
}

// Round 5
// 2550.428 us; speedup vs baseline: 3.1756x; 1.5051x over previous
//
#include <hip/hip_runtime.h>
#include <hip/hip_bf16.h>
#include <math.h>

using bf16 = __hip_bfloat16;
typedef __attribute__((ext_vector_type(8))) short short8;
typedef __attribute__((ext_vector_type(4))) float floatx4;

#define NB   32      // batch
#define NK   32      // protein slots
#define NNODE 2048   // nodes per graph
#define NEDGE 16384  // edges per graph
#define ND   768     // hidden dim
#define NHH  12      // heads
#define DHH  64      // head dim
#define NFF  3072    // ff dim
#define NG   64      // graphs = 2*NK
#define LTR  4
#define GC   8       // graphs per GNN chunk

static __device__ __forceinline__ float b2f(bf16 x) { return __bfloat162float(x); }
static __device__ __forceinline__ bf16 f2b(float x) { return __float2bfloat16(x); }

// dtype-flexible external load: f32 -> fp32 storage, else bf16 storage
static __device__ __forceinline__ float ldf(const void* p, size_t i, bool f32) {
    return f32 ? ((const float*)p)[i] : b2f(((const bf16*)p)[i]);
}

// ---------------- dtype detection ----------------
// emb_ln_scale is all ones: fp32 word0 = 0x3F800000, bf16-pair word0 = 0x3F803F80
__global__ void detect_dtype_kernel(const void* __restrict__ eln_s, int* __restrict__ flag) {
    if (threadIdx.x == 0 && blockIdx.x == 0) {
        unsigned w = ((const unsigned*)eln_s)[0];
        flag[0] = (w == 0x3F800000u) ? 1 : 0;
    }
}

// ---------------- weight conversion: [R][Cn] (fp32/bf16) -> bf16 [Cn][R] ----------------
__device__ __forceinline__ void conv_tile(const void* __restrict__ src, size_t srcOff,
                                          bf16* __restrict__ dst, int R, int Cn,
                                          int tr, int tc, bool f32, int t,
                                          bf16 (*tile)[65]) {
    int r0 = tr * 64, c0 = tc * 64;
    #pragma unroll
    for (int p = 0; p < 16; ++p) {
        int idx = t + p * 256;
        int r = idx >> 6, c = idx & 63;
        tile[r][c] = f2b(ldf(src, srcOff + (size_t)(r0 + r) * Cn + c0 + c, f32));
    }
    __syncthreads();
    #pragma unroll
    for (int p = 0; p < 16; ++p) {
        int idx = t + p * 256;
        int c = idx >> 6, r = idx & 63;
        dst[(size_t)(c0 + c) * R + r0 + r] = tile[r][c];
    }
}

__global__ __launch_bounds__(256) void convert_gnn_kernel(const void* __restrict__ gnnW,
                                                          bf16* __restrict__ gnnT,
                                                          const int* __restrict__ flag) {
    __shared__ bf16 tile[64][65];
    bool f32 = flag[0] != 0;
    int bid = blockIdx.x;                 // 2 * 144
    int id = bid / 144, tl = bid % 144;
    conv_tile(gnnW, (size_t)id * 589824, gnnT + (size_t)id * 589824,
              768, 768, tl / 12, tl % 12, f32, threadIdx.x, tile);
}

__global__ __launch_bounds__(256) void convert_layer_kernel(
    const void* __restrict__ Wq, const void* __restrict__ Wk, const void* __restrict__ Wv,
    const void* __restrict__ Wo, const void* __restrict__ W1, const void* __restrict__ W2,
    int l, bf16* __restrict__ qkvT, bf16* __restrict__ oT,
    bf16* __restrict__ w1T, bf16* __restrict__ w2T, const int* __restrict__ flag) {
    __shared__ bf16 tile[64][65];
    bool f32 = flag[0] != 0;
    int bid = blockIdx.x, t = threadIdx.x;   // 1728 blocks
    if (bid < 432) {
        int m = bid / 144, tl = bid % 144;
        const void* src = (m == 0) ? Wq : ((m == 1) ? Wk : Wv);
        conv_tile(src, (size_t)l * 589824, qkvT + (size_t)m * 589824,
                  768, 768, tl / 12, tl % 12, f32, t, tile);
    } else if (bid < 576) {
        int tl = bid - 432;
        conv_tile(Wo, (size_t)l * 589824, oT, 768, 768, tl / 12, tl % 12, f32, t, tile);
    } else if (bid < 1152) {
        int tl = bid - 576;
        conv_tile(W1, (size_t)l * 768 * 3072, w1T, 768, 3072, tl / 48, tl % 48, f32, t, tile);
    } else {
        int tl = bid - 1152;
        conv_tile(W2, (size_t)l * 3072 * 768, w2T, 3072, 768, tl / 12, tl % 12, f32, t, tile);
    }
}

// pack all biases to fp32: [0,1536)=gnn, then per layer 6912: qkv(2304),o(768),b1(3072),b2(768)
__global__ __launch_bounds__(256) void pack_bias_kernel(
    const void* __restrict__ gnnb, const void* __restrict__ bq, const void* __restrict__ bk,
    const void* __restrict__ bv, const void* __restrict__ bo, const void* __restrict__ b1,
    const void* __restrict__ b2, float* __restrict__ out, const int* __restrict__ flag) {
    bool f32 = flag[0] != 0;
    int i = blockIdx.x * 256 + threadIdx.x;
    if (i >= 1536 + LTR * 6912) return;
    float v;
    if (i < 1536) v = ldf(gnnb, i, f32);
    else {
        int j = i - 1536, l = j / 6912, r = j % 6912;
        if      (r <  768) v = ldf(bq, l * 768 + r, f32);
        else if (r < 1536) v = ldf(bk, l * 768 + r - 768, f32);
        else if (r < 2304) v = ldf(bv, l * 768 + r - 1536, f32);
        else if (r < 3072) v = ldf(bo, l * 768 + r - 2304, f32);
        else if (r < 6144) v = ldf(b1, l * 3072 + r - 3072, f32);
        else               v = ldf(b2, l * 768 + r - 6144, f32);
    }
    out[i] = v;
}

// ---------------- CSR build ----------------
__global__ __launch_bounds__(256) void count_deg_kernel(const int* __restrict__ edge0,
                                                        const int* __restrict__ edge1,
                                                        int* __restrict__ deg) {
    int gid = blockIdx.x;            // 64 graphs * 64 chunks
    int g = gid >> 6, chunk = gid & 63;
    const int* ep = (g < NK) ? (edge0 + (size_t)g * 2 * NEDGE)
                             : (edge1 + (size_t)(g - NK) * 2 * NEDGE);
    int e = chunk * 256 + threadIdx.x;
    int dst = ep[NEDGE + e];
    atomicAdd(&deg[g * NNODE + dst], 1);
}

__global__ __launch_bounds__(256) void scan_deg_kernel(int* __restrict__ deg,
                                                       int* __restrict__ indptr) {
    int g = blockIdx.x, t = threadIdx.x;
    __shared__ int sums[256];
    int loc[8]; int s = 0;
    #pragma unroll
    for (int i = 0; i < 8; ++i) { loc[i] = deg[g * NNODE + t * 8 + i]; s += loc[i]; }
    sums[t] = s; __syncthreads();
    for (int off = 1; off < 256; off <<= 1) {
        int v = (t >= off) ? sums[t - off] : 0;
        __syncthreads();
        sums[t] += v;
        __syncthreads();
    }
    int run = sums[t] - s;           // exclusive prefix
    #pragma unroll
    for (int i = 0; i < 8; ++i) {
        indptr[g * (NNODE + 1) + t * 8 + i] = run;
        deg[g * NNODE + t * 8 + i] = run;   // becomes cursor
        run += loc[i];
    }
    if (t == 255) indptr[g * (NNODE + 1) + NNODE] = run;
}

__global__ __launch_bounds__(256) void fill_csr_kernel(const int* __restrict__ edge0,
                                                       const int* __restrict__ edge1,
                                                       int* __restrict__ cursor,
                                                       int* __restrict__ csr_src) {
    int gid = blockIdx.x;
    int g = gid >> 6, chunk = gid & 63;
    const int* ep = (g < NK) ? (edge0 + (size_t)g * 2 * NEDGE)
                             : (edge1 + (size_t)(g - NK) * 2 * NEDGE);
    int e = chunk * 256 + threadIdx.x;
    int src = ep[e];
    int dst = ep[NEDGE + e];
    int p = atomicAdd(&cursor[g * NNODE + dst], 1);
    csr_src[(size_t)g * NEDGE + p] = src;
}

// ---------------- GNN ----------------
__global__ __launch_bounds__(256) void gather_embed_kernel(const int* __restrict__ x0,
                                                           const int* __restrict__ x1,
                                                           const void* __restrict__ emb,
                                                           bf16* __restrict__ hC, int g0,
                                                           const int* __restrict__ flag) {
    bool f32 = flag[0] != 0;
    int gn = blockIdx.x;             // gl*2048 + n
    int gl = gn >> 11, n = gn & 2047;
    int g = g0 + gl;
    int id = (g < NK) ? x0[g * NNODE + n] : x1[(g - NK) * NNODE + n];
    bf16* dst = hC + (size_t)gn * ND;
    for (int d = threadIdx.x; d < ND; d += 256)
        dst[d] = f2b(ldf(emb, (size_t)id * ND + d, f32));
}

// x_out[n] = h[n] + sum_{e in CSR(n)} h[src_e]
__global__ __launch_bounds__(256) void gnn_aggregate_kernel(const bf16* __restrict__ hC,
                                                            const int* __restrict__ indptr,
                                                            const int* __restrict__ csr_src,
                                                            bf16* __restrict__ xC, int g0) {
    int gn = blockIdx.x;
    int gl = gn >> 11, n = gn & 2047;
    int g = g0 + gl;
    int beg = indptr[g * (NNODE + 1) + n];
    int end = indptr[g * (NNODE + 1) + n + 1];
    const bf16* hg = hC + (size_t)gl * NNODE * ND;
    const int* cs = csr_src + (size_t)g * NEDGE;
    int t = threadIdx.x;
    float acc[3];
    #pragma unroll
    for (int e2 = 0; e2 < 3; ++e2) acc[e2] = b2f(hg[(size_t)n * ND + t + e2 * 256]);
    for (int e = beg; e < end; ++e) {
        int s = cs[e];
        #pragma unroll
        for (int e2 = 0; e2 < 3; ++e2) acc[e2] += b2f(hg[(size_t)s * ND + t + e2 * 256]);
    }
    #pragma unroll
    for (int e2 = 0; e2 < 3; ++e2) xC[(size_t)gn * ND + t + e2 * 256] = f2b(acc[e2]);
}

// one block per (batch value, graph-in-chunk); sorted batch -> binary search; writes mean
__global__ __launch_bounds__(256) void readout_kernel(const bf16* __restrict__ hC,
                                                      const int* __restrict__ batch0,
                                                      const int* __restrict__ batch1,
                                                      float* __restrict__ pooled, int g0) {
    int gl = blockIdx.y;
    int g = g0 + gl;
    int b = blockIdx.x;
    const int* bp = (g < NK) ? (batch0 + (size_t)g * NNODE)
                             : (batch1 + (size_t)(g - NK) * NNODE);
    int lo = 0, hi = NNODE;
    while (lo < hi) { int mid = (lo + hi) >> 1; if (bp[mid] < b) lo = mid + 1; else hi = mid; }
    int start = lo;
    hi = NNODE;
    while (lo < hi) { int mid = (lo + hi) >> 1; if (bp[mid] < b + 1) lo = mid + 1; else hi = mid; }
    int end = lo;
    int t = threadIdx.x;
    float acc[3] = {0.f, 0.f, 0.f};
    const bf16* hg = hC + (size_t)gl * NNODE * ND;
    for (int n = start; n < end; ++n) {
        #pragma unroll
        for (int e = 0; e < 3; ++e)
            acc[e] += b2f(hg[(size_t)n * ND + t + e * 256]);
    }
    float inv = 1.f / (float)max(end - start, 1);
    #pragma unroll
    for (int e = 0; e < 3; ++e)
        pooled[((size_t)g * NB + b) * ND + t + e * 256] = acc[e] * inv;
}

// ---------------- GEMM TN (bf16 MFMA 16x16x32, 128x128 tile, 4 waves) ----------------
// C[M][N] = act(A[M][K] @ B[K][N] + bias[N]), BT = B^T stored [N][K] bf16, bias fp32.
// act: 0=none 1=relu 2=gelu(tanh-approx via sigmoid identity)
__global__ __launch_bounds__(256) void gemm_tn(const bf16* __restrict__ A,
                                               const bf16* __restrict__ BT,
                                               const float* __restrict__ bias,
                                               void* __restrict__ C,
                                               int M, int K, int N,
                                               int act, int outF32) {
    __shared__ bf16 lA[128][32];     // [m][k]
    __shared__ bf16 lB[128][32];     // [n][k]
    int nTilesN = N >> 7;
    int bcol = blockIdx.x % nTilesN;
    int brow = blockIdx.x / nTilesN;
    int t = threadIdx.x;
    int wave = t >> 6, lane = t & 63;
    int wr = wave >> 1, wc = wave & 1;
    int l15 = lane & 15, quad = lane >> 4;
    const int row0 = brow << 7, col0 = bcol << 7;
    // staging map: u in {t, t+256}: row = u>>2, k8 = (u&3)*8 -> LDS addr = 16*u bytes
    const int sr0 = t >> 2, sk0 = (t & 3) * 8;
    const bf16* Abase = A + (size_t)row0 * K + sk0;
    const bf16* Bbase = BT + (size_t)col0 * K + sk0;

    floatx4 acc[4][4] = {};

    for (int k0 = 0; k0 < K; k0 += 32) {
        uint4 a0 = *reinterpret_cast<const uint4*>(Abase + (size_t)sr0 * K + k0);
        uint4 a1 = *reinterpret_cast<const uint4*>(Abase + (size_t)(sr0 + 64) * K + k0);
        uint4 b0 = *reinterpret_cast<const uint4*>(Bbase + (size_t)sr0 * K + k0);
        uint4 b1 = *reinterpret_cast<const uint4*>(Bbase + (size_t)(sr0 + 64) * K + k0);
        __syncthreads();             // previous iter's ds_reads done before overwrite
        *reinterpret_cast<uint4*>(&lA[sr0][sk0])      = a0;
        *reinterpret_cast<uint4*>(&lA[sr0 + 64][sk0]) = a1;
        *reinterpret_cast<uint4*>(&lB[sr0][sk0])      = b0;
        *reinterpret_cast<uint4*>(&lB[sr0 + 64][sk0]) = b1;
        __syncthreads();
        short8 afr[4], bfr[4];
        #pragma unroll
        for (int i = 0; i < 4; ++i)
            afr[i] = *reinterpret_cast<const short8*>(&lA[wr * 64 + i * 16 + l15][quad * 8]);
        #pragma unroll
        for (int j = 0; j < 4; ++j)
            bfr[j] = *reinterpret_cast<const short8*>(&lB[wc * 64 + j * 16 + l15][quad * 8]);
        #pragma unroll
        for (int i = 0; i < 4; ++i)
            #pragma unroll
            for (int j = 0; j < 4; ++j)
                acc[i][j] = __builtin_amdgcn_mfma_f32_16x16x32_bf16(afr[i], bfr[j], acc[i][j], 0, 0, 0);
    }
    // epilogue: D[row=4*quad+r][col=l15] per 16x16 tile (verified m89/m91 layout)
    #pragma unroll
    for (int i = 0; i < 4; ++i) {
        int rbase = row0 + wr * 64 + i * 16 + quad * 4;
        #pragma unroll
        for (int j = 0; j < 4; ++j) {
            int c = col0 + wc * 64 + j * 16 + l15;
            float bv = bias[c];
            #pragma unroll
            for (int r = 0; r < 4; ++r) {
                float v = acc[i][j][r] + bv;
                if (act == 1) v = fmaxf(v, 0.f);
                else if (act == 2) {
                    float x = v;
                    float u = 1.5957691216057308f * (x + 0.044715f * x * x * x);
                    v = x / (1.f + __expf(-u));   // 0.5x(1+tanh(u/2)) == x*sigmoid(u)
                }
                size_t idx = (size_t)(rbase + r) * N + c;
                if (outF32) ((float*)C)[idx] = v;
                else        ((bf16*)C)[idx] = f2b(v);
            }
        }
    }
}

// ---------------- LayerNorm helpers ----------------
__device__ __forceinline__ void block_ln_768(float (&x)[3], int t,
                                             const void* __restrict__ s,
                                             const void* __restrict__ b,
                                             size_t sOff, bool f32,
                                             float (&y)[3], float* red) {
    float loc = x[0] + x[1] + x[2];
    red[t] = loc; __syncthreads();
    for (int off = 128; off > 0; off >>= 1) {
        if (t < off) red[t] += red[t + off];
        __syncthreads();
    }
    float mean = red[0] * (1.f / 768.f);
    __syncthreads();
    float vs = 0.f;
    #pragma unroll
    for (int e = 0; e < 3; ++e) { float d = x[e] - mean; vs += d * d; }
    red[t] = vs; __syncthreads();
    for (int off = 128; off > 0; off >>= 1) {
        if (t < off) red[t] += red[t + off];
        __syncthreads();
    }
    float var = red[0] * (1.f / 768.f);
    __syncthreads();
    float inv = rsqrtf(var + 1e-12f);
    #pragma unroll
    for (int e = 0; e < 3; ++e) {
        int d = t + e * 256;
        y[e] = (x[e] - mean) * inv * ldf(s, sOff + d, f32) + ldf(b, sOff + d, f32);
    }
}

__global__ __launch_bounds__(256) void combine_embed_ln_kernel(
    const void* __restrict__ raw, const float* __restrict__ pooled,
    const int* __restrict__ role_ids, const int* __restrict__ pos_ids, const int* __restrict__ hop_ids,
    const void* __restrict__ role_emb, const void* __restrict__ pos_emb, const void* __restrict__ hop_emb,
    const void* __restrict__ lns, const void* __restrict__ lnb,
    float* __restrict__ hT, bf16* __restrict__ hbf,
    const int* __restrict__ flag) {
    bool f32 = flag[0] != 0;
    __shared__ float red[256];
    int token = blockIdx.x;          // b*NK + k
    int b = token >> 5, k = token & 31;
    int t = threadIdx.x;
    int rid = role_ids[b * NK + k];
    int pid = pos_ids[b * NK + k];
    int hid = hop_ids[b * NK + k];
    float x[3], y[3];
    #pragma unroll
    for (int e = 0; e < 3; ++e) {
        int d = t + e * 256;
        float p0 = pooled[((size_t)k * NB + b) * ND + d];
        float p1 = pooled[((size_t)(NK + k) * NB + b) * ND + d];
        x[e] = ldf(raw, (size_t)token * ND + d, f32) + p0 + p1
             + ldf(role_emb, (size_t)rid * ND + d, f32)
             + ldf(pos_emb, (size_t)pid * ND + d, f32)
             + ldf(hop_emb, (size_t)hid * ND + d, f32);
    }
    block_ln_768(x, t, lns, lnb, 0, f32, y, red);
    #pragma unroll
    for (int e = 0; e < 3; ++e) {
        int d = t + e * 256;
        hT[(size_t)token * ND + d] = y[e];
        hbf[(size_t)token * ND + d] = f2b(y[e]);
    }
}

// extOut=0: write bf16 to outp (internal). extOut=1: write d_out in detected dtype.
__global__ __launch_bounds__(256) void add_ln_kernel(float* __restrict__ hT,
                                                     const float* __restrict__ addv,
                                                     const void* __restrict__ lns,
                                                     const void* __restrict__ lnb,
                                                     unsigned long long sOff,
                                                     void* __restrict__ outp, int extOut,
                                                     const int* __restrict__ flag) {
    bool f32 = flag[0] != 0;
    __shared__ float red[256];
    int token = blockIdx.x;
    int t = threadIdx.x;
    float x[3], y[3];
    #pragma unroll
    for (int e = 0; e < 3; ++e) {
        int d = t + e * 256;
        x[e] = hT[(size_t)token * ND + d] + addv[(size_t)token * ND + d];
    }
    block_ln_768(x, t, lns, lnb, sOff, f32, y, red);
    #pragma unroll
    for (int e = 0; e < 3; ++e) {
        int d = t + e * 256;
        size_t idx = (size_t)token * ND + d;
        hT[idx] = y[e];
        if (extOut && f32) ((float*)outp)[idx] = y[e];
        else               ((bf16*)outp)[idx] = f2b(y[e]);
    }
}

// ---------------- attention (per (b,head) 32x32), qkv fused buffer [M][2304] ----------------
__global__ __launch_bounds__(256) void attn_kernel(const bf16* __restrict__ qkv,
                                                   bf16* __restrict__ ctx) {
    int blk = blockIdx.x;            // b*NHH + h
    int b = blk / NHH, h = blk % NHH;
    __shared__ float lq[NK][DHH], lk[NK][DHH], lv[NK][DHH];
    __shared__ float ls[NK][NK];
    int t = threadIdx.x;
    for (int i = t; i < NK * DHH; i += 256) {
        int tok = i >> 6, d = i & 63;
        size_t base = ((size_t)(b * NK + tok)) * (3 * ND) + h * DHH + d;
        lq[tok][d] = b2f(qkv[base]);
        lk[tok][d] = b2f(qkv[base + ND]);
        lv[tok][d] = b2f(qkv[base + 2 * ND]);
    }
    __syncthreads();
    const float scale = 0.125f;      // 1/sqrt(64)
    for (int i = t; i < NK * NK; i += 256) {
        int qi = i >> 5, kj = i & 31;
        float s = 0.f;
        #pragma unroll
        for (int d = 0; d < DHH; ++d) s += lq[qi][d] * lk[kj][d];
        ls[qi][kj] = s * scale;
    }
    __syncthreads();
    if (t < NK) {
        float m = -1e30f;
        for (int j = 0; j < NK; ++j) m = fmaxf(m, ls[t][j]);
        float sum = 0.f;
        for (int j = 0; j < NK; ++j) { float e = expf(ls[t][j] - m); ls[t][j] = e; sum += e; }
        float inv = 1.f / sum;
        for (int j = 0; j < NK; ++j) ls[t][j] *= inv;
    }
    __syncthreads();
    for (int i = t; i < NK * DHH; i += 256) {
        int qi = i >> 6, d = i & 63;
        float s = 0.f;
        #pragma unroll
        for (int j = 0; j < NK; ++j) s += ls[qi][j] * lv[j][d];
        ctx[((size_t)(b * NK + qi)) * ND + h * DHH + d] = f2b(s);
    }
}

// ---------------- launch ----------------
extern "C" void kernel_launch(void* const* d_in, const int* in_sizes, int n_in,
                              void* d_out, int out_size, void* d_ws, size_t ws_size,
                              hipStream_t stream) {
    const void* raw      = d_in[0];
    const int*  x0       = (const int*)d_in[1];
    const int*  edge0    = (const int*)d_in[2];
    const int*  batch0   = (const int*)d_in[3];
    const int*  x1       = (const int*)d_in[4];
    const int*  edge1    = (const int*)d_in[5];
    const int*  batch1   = (const int*)d_in[6];
    const int*  role_ids = (const int*)d_in[7];
    const int*  pos_ids  = (const int*)d_in[8];
    const int*  hop_ids  = (const int*)d_in[9];
    const void* amino    = d_in[10];
    const void* gnnW     = d_in[11];
    const void* gnnb     = d_in[12];
    const void* role_emb = d_in[13];
    const void* pos_emb  = d_in[14];
    const void* hop_emb  = d_in[15];
    const void* eln_s    = d_in[16];
    const void* eln_b    = d_in[17];
    const void* Wq       = d_in[18];
    const void* bq       = d_in[19];
    const void* Wk       = d_in[20];
    const void* bk       = d_in[21];
    const void* Wv       = d_in[22];
    const void* bv       = d_in[23];
    const void* Wo       = d_in[24];
    const void* bo       = d_in[25];
    const void* ln1_s    = d_in[26];
    const void* ln1_b    = d_in[27];
    const void* W1       = d_in[28];
    const void* b1       = d_in[29];
    const void* W2       = d_in[30];
    const void* b2       = d_in[31];
    const void* ln2_s    = d_in[32];
    const void* ln2_b    = d_in[33];

    char* ws = (char*)d_ws;
    size_t off = 0;
    auto alloc = [&](size_t bytes) -> void* {
        void* p = ws + off;
        off = (off + bytes + 255) & ~(size_t)255;
        return p;
    };
    int*   dflag   = (int*)alloc(256);
    float* pooled  = (float*)alloc((size_t)NG * NB * ND * 4);          // 6.29 MB
    int*   indptr  = (int*)alloc((size_t)NG * (NNODE + 1) * 4);        // 524 KB
    int*   csr_src = (int*)alloc((size_t)NG * NEDGE * 4);              // 4.19 MB
    int*   degcur  = (int*)alloc((size_t)NG * NNODE * 4);              // 524 KB
    bf16*  gnnT    = (bf16*)alloc((size_t)2 * ND * ND * 2);            // 2.36 MB
    bf16*  qkvT    = (bf16*)alloc((size_t)3 * ND * ND * 2);            // 3.54 MB (per-layer reuse)
    bf16*  oT      = (bf16*)alloc((size_t)ND * ND * 2);                // 1.18 MB
    bf16*  w1T     = (bf16*)alloc((size_t)ND * NFF * 2);               // 4.72 MB
    bf16*  w2T     = (bf16*)alloc((size_t)NFF * ND * 2);               // 4.72 MB
    float* biasPk  = (float*)alloc((size_t)(1536 + LTR * 6912) * 4);   // 117 KB
    // big region: GNN chunk buffers, later aliased by transformer buffers (~50 MB)
    char* bigbase = (char*)alloc((size_t)GC * NNODE * ND * 2 * 2);
    bf16* hC = (bf16*)bigbase;
    bf16* xC = (bf16*)(bigbase + (size_t)GC * NNODE * ND * 2);
    size_t toff = 0;
    auto talloc = [&](size_t bytes) -> void* {
        void* p = bigbase + toff;
        toff = (toff + bytes + 255) & ~(size_t)255;
        return p;
    };
    float* hT    = (float*)talloc((size_t)NB * NK * ND * 4);
    bf16*  hbf   = (bf16*)talloc((size_t)NB * NK * ND * 2);
    bf16*  qkvb  = (bf16*)talloc((size_t)NB * NK * 3 * ND * 2);
    bf16*  ctxb  = (bf16*)talloc((size_t)NB * NK * ND * 2);
    float* resid = (float*)talloc((size_t)NB * NK * ND * 4);
    bf16*  ffbuf = (bf16*)talloc((size_t)NB * NK * NFF * 2);

    auto gemm = [&](const bf16* A, const bf16* BT, const float* bias, void* C,
                    int M, int K, int N, int act, int outF32) {
        int blocks = (M >> 7) * (N >> 7);
        gemm_tn<<<blocks, 256, 0, stream>>>(A, BT, bias, C, M, K, N, act, outF32);
    };

    // ---- dtype detection (precedes all external-input readers) ----
    detect_dtype_kernel<<<1, 64, 0, stream>>>(eln_s, dflag);

    // ---- weight/bias preconversion (gnn + biases; transformer weights per layer) ----
    convert_gnn_kernel<<<288, 256, 0, stream>>>(gnnW, gnnT, dflag);
    pack_bias_kernel<<<(1536 + LTR * 6912 + 255) / 256, 256, 0, stream>>>(
        gnnb, bq, bk, bv, bo, b1, b2, biasPk, dflag);

    // ---- CSR build ----
    hipMemsetAsync(degcur, 0, (size_t)NG * NNODE * 4, stream);
    count_deg_kernel<<<NG * 64, 256, 0, stream>>>(edge0, edge1, degcur);
    scan_deg_kernel<<<NG, 256, 0, stream>>>(degcur, indptr);
    fill_csr_kernel<<<NG * 64, 256, 0, stream>>>(edge0, edge1, degcur, csr_src);

    // ---- GNN, chunked over graphs ----
    for (int g0 = 0; g0 < NG; g0 += GC) {
        gather_embed_kernel<<<GC * NNODE, 256, 0, stream>>>(x0, x1, amino, hC, g0, dflag);
        for (int l = 0; l < 2; ++l) {
            gnn_aggregate_kernel<<<GC * NNODE, 256, 0, stream>>>(hC, indptr, csr_src, xC, g0);
            gemm(xC, gnnT + (size_t)l * ND * ND, biasPk + l * ND, hC,
                 GC * NNODE, ND, ND, /*relu*/1, /*outF32*/0);
        }
        dim3 grid(NB, GC);
        readout_kernel<<<grid, 256, 0, stream>>>(hC, batch0, batch1, pooled, g0);
    }

    // ---- embeddings + LN ----
    combine_embed_ln_kernel<<<NB * NK, 256, 0, stream>>>(
        raw, pooled, role_ids, pos_ids, hop_ids,
        role_emb, pos_emb, hop_emb, eln_s, eln_b, hT, hbf, dflag);

    // ---- transformer ----
    const int M = NB * NK;
    for (int l = 0; l < LTR; ++l) {
        convert_layer_kernel<<<1728, 256, 0, stream>>>(Wq, Wk, Wv, Wo, W1, W2, l,
                                                       qkvT, oT, w1T, w2T, dflag);
        const float* lb = biasPk + 1536 + l * 6912;
        gemm(hbf, qkvT, lb, qkvb, M, ND, 3 * ND, 0, 0);                 // fused QKV
        attn_kernel<<<NB * NHH, 256, 0, stream>>>(qkvb, ctxb);
        gemm(ctxb, oT, lb + 2304, resid, M, ND, ND, 0, /*outF32*/1);
        add_ln_kernel<<<M, 256, 0, stream>>>(hT, resid, ln1_s, ln1_b,
                                             (unsigned long long)l * ND, hbf, 0, dflag);
        gemm(hbf, w1T, lb + 3072, ffbuf, M, ND, NFF, /*gelu*/2, 0);
        gemm(ffbuf, w2T, lb + 6144, resid, M, NFF, ND, 0, /*outF32*/1);
        int ext = (l == LTR - 1) ? 1 : 0;
        void* outb = ext ? d_out : (void*)hbf;
        add_ln_kernel<<<M, 256, 0, stream>>>(hT, resid, ln2_s, ln2_b,
                                             (unsigned long long)l * ND, outb, ext, dflag);
    }
}

// Round 6
// 2158.724 us; speedup vs baseline: 3.7518x; 1.1815x over previous
//
#include <hip/hip_runtime.h>
#include <hip/hip_bf16.h>
#include <math.h>

using bf16 = __hip_bfloat16;
typedef __attribute__((ext_vector_type(8))) short short8;
typedef __attribute__((ext_vector_type(4))) float floatx4;
typedef __attribute__((ext_vector_type(4))) short short4v;

#define NB   32      // batch
#define NK   32      // protein slots
#define NNODE 2048   // nodes per graph
#define NEDGE 16384  // edges per graph
#define ND   768     // hidden dim
#define NHH  12      // heads
#define DHH  64      // head dim
#define NFF  3072    // ff dim
#define NG   64      // graphs = 2*NK
#define LTR  4

static __device__ __forceinline__ float b2f(bf16 x) { return __bfloat162float(x); }
static __device__ __forceinline__ bf16 f2b(float x) { return __float2bfloat16(x); }
static __device__ __forceinline__ float bs2f(short s) {
    unsigned u = ((unsigned)(unsigned short)s) << 16;
    float f; __builtin_memcpy(&f, &u, 4); return f;
}
static __device__ __forceinline__ short f2bs(float x) {
    bf16 h = f2b(x); short s; __builtin_memcpy(&s, &h, 2); return s;
}

// dtype-flexible external load: f32 -> fp32 storage, else bf16 storage
static __device__ __forceinline__ float ldf(const void* p, size_t i, bool f32) {
    return f32 ? ((const float*)p)[i] : b2f(((const bf16*)p)[i]);
}

// ---------------- dtype detection ----------------
__global__ void detect_dtype_kernel(const void* __restrict__ eln_s, int* __restrict__ flag) {
    if (threadIdx.x == 0 && blockIdx.x == 0) {
        unsigned w = ((const unsigned*)eln_s)[0];
        flag[0] = (w == 0x3F800000u) ? 1 : 0;
    }
}

// ---------------- weight conversion: [R][Cn] (fp32/bf16) -> bf16 [Cn][R] ----------------
__device__ __forceinline__ void conv_tile(const void* __restrict__ src, size_t srcOff,
                                          bf16* __restrict__ dst, int R, int Cn,
                                          int tr, int tc, bool f32, int t,
                                          bf16 (*tile)[65]) {
    int r0 = tr * 64, c0 = tc * 64;
    #pragma unroll
    for (int p = 0; p < 16; ++p) {
        int idx = t + p * 256;
        int r = idx >> 6, c = idx & 63;
        tile[r][c] = f2b(ldf(src, srcOff + (size_t)(r0 + r) * Cn + c0 + c, f32));
    }
    __syncthreads();
    #pragma unroll
    for (int p = 0; p < 16; ++p) {
        int idx = t + p * 256;
        int c = idx >> 6, r = idx & 63;
        dst[(size_t)(c0 + c) * R + r0 + r] = tile[r][c];
    }
}

__global__ __launch_bounds__(256) void convert_gnn_kernel(const void* __restrict__ gnnW,
                                                          bf16* __restrict__ gnnT,
                                                          const int* __restrict__ flag) {
    __shared__ bf16 tile[64][65];
    bool f32 = flag[0] != 0;
    int bid = blockIdx.x;                 // 2 * 144
    int id = bid / 144, tl = bid % 144;
    conv_tile(gnnW, (size_t)id * 589824, gnnT + (size_t)id * 589824,
              768, 768, tl / 12, tl % 12, f32, threadIdx.x, tile);
}

__global__ __launch_bounds__(256) void convert_layer_kernel(
    const void* __restrict__ Wq, const void* __restrict__ Wk, const void* __restrict__ Wv,
    const void* __restrict__ Wo, const void* __restrict__ W1, const void* __restrict__ W2,
    int l, bf16* __restrict__ qkvT, bf16* __restrict__ oT,
    bf16* __restrict__ w1T, bf16* __restrict__ w2T, const int* __restrict__ flag) {
    __shared__ bf16 tile[64][65];
    bool f32 = flag[0] != 0;
    int bid = blockIdx.x, t = threadIdx.x;   // 1728 blocks
    if (bid < 432) {
        int m = bid / 144, tl = bid % 144;
        const void* src = (m == 0) ? Wq : ((m == 1) ? Wk : Wv);
        conv_tile(src, (size_t)l * 589824, qkvT + (size_t)m * 589824,
                  768, 768, tl / 12, tl % 12, f32, t, tile);
    } else if (bid < 576) {
        int tl = bid - 432;
        conv_tile(Wo, (size_t)l * 589824, oT, 768, 768, tl / 12, tl % 12, f32, t, tile);
    } else if (bid < 1152) {
        int tl = bid - 576;
        conv_tile(W1, (size_t)l * 768 * 3072, w1T, 768, 3072, tl / 48, tl % 48, f32, t, tile);
    } else {
        int tl = bid - 1152;
        conv_tile(W2, (size_t)l * 3072 * 768, w2T, 3072, 768, tl / 12, tl % 12, f32, t, tile);
    }
}

// pack biases fp32: [0,1536)=gnn, then per layer 6912: qkv(2304),o(768),b1(3072),b2(768)
__global__ __launch_bounds__(256) void pack_bias_kernel(
    const void* __restrict__ gnnb, const void* __restrict__ bq, const void* __restrict__ bk,
    const void* __restrict__ bv, const void* __restrict__ bo, const void* __restrict__ b1,
    const void* __restrict__ b2, float* __restrict__ out, const int* __restrict__ flag) {
    bool f32 = flag[0] != 0;
    int i = blockIdx.x * 256 + threadIdx.x;
    if (i >= 1536 + LTR * 6912) return;
    float v;
    if (i < 1536) v = ldf(gnnb, i, f32);
    else {
        int j = i - 1536, l = j / 6912, r = j % 6912;
        if      (r <  768) v = ldf(bq, l * 768 + r, f32);
        else if (r < 1536) v = ldf(bk, l * 768 + r - 768, f32);
        else if (r < 2304) v = ldf(bv, l * 768 + r - 1536, f32);
        else if (r < 3072) v = ldf(bo, l * 768 + r - 2304, f32);
        else if (r < 6144) v = ldf(b1, l * 3072 + r - 3072, f32);
        else               v = ldf(b2, l * 768 + r - 6144, f32);
    }
    out[i] = v;
}

// ---------------- CSR build ----------------
__global__ __launch_bounds__(256) void count_deg_kernel(const int* __restrict__ edge0,
                                                        const int* __restrict__ edge1,
                                                        int* __restrict__ deg) {
    int gid = blockIdx.x;            // 64 graphs * 64 chunks
    int g = gid >> 6, chunk = gid & 63;
    const int* ep = (g < NK) ? (edge0 + (size_t)g * 2 * NEDGE)
                             : (edge1 + (size_t)(g - NK) * 2 * NEDGE);
    int e = chunk * 256 + threadIdx.x;
    int dst = ep[NEDGE + e];
    atomicAdd(&deg[g * NNODE + dst], 1);
}

__global__ __launch_bounds__(256) void scan_deg_kernel(int* __restrict__ deg,
                                                       int* __restrict__ indptr) {
    int g = blockIdx.x, t = threadIdx.x;
    __shared__ int sums[256];
    int loc[8]; int s = 0;
    #pragma unroll
    for (int i = 0; i < 8; ++i) { loc[i] = deg[g * NNODE + t * 8 + i]; s += loc[i]; }
    sums[t] = s; __syncthreads();
    for (int off = 1; off < 256; off <<= 1) {
        int v = (t >= off) ? sums[t - off] : 0;
        __syncthreads();
        sums[t] += v;
        __syncthreads();
    }
    int run = sums[t] - s;           // exclusive prefix
    #pragma unroll
    for (int i = 0; i < 8; ++i) {
        indptr[g * (NNODE + 1) + t * 8 + i] = run;
        deg[g * NNODE + t * 8 + i] = run;   // becomes cursor
        run += loc[i];
    }
    if (t == 255) indptr[g * (NNODE + 1) + NNODE] = run;
}

__global__ __launch_bounds__(256) void fill_csr_kernel(const int* __restrict__ edge0,
                                                       const int* __restrict__ edge1,
                                                       int* __restrict__ cursor,
                                                       int* __restrict__ csr_src) {
    int gid = blockIdx.x;
    int g = gid >> 6, chunk = gid & 63;
    const int* ep = (g < NK) ? (edge0 + (size_t)g * 2 * NEDGE)
                             : (edge1 + (size_t)(g - NK) * 2 * NEDGE);
    int e = chunk * 256 + threadIdx.x;
    int src = ep[e];
    int dst = ep[NEDGE + e];
    int p = atomicAdd(&cursor[g * NNODE + dst], 1);
    csr_src[(size_t)g * NEDGE + p] = src;
}

// ---------------- GNN (192-thread blocks; lane handles 4 bf16 = 8 B) ----------------
__global__ __launch_bounds__(192) void gather_embed_kernel(const int* __restrict__ x0,
                                                           const int* __restrict__ x1,
                                                           const void* __restrict__ emb,
                                                           bf16* __restrict__ hC, int g0,
                                                           const int* __restrict__ flag) {
    bool f32 = flag[0] != 0;
    int gn = blockIdx.x;             // gl*2048 + n
    int gl = gn >> 11, n = gn & 2047;
    int g = g0 + gl;
    int id = (g < NK) ? x0[g * NNODE + n] : x1[(g - NK) * NNODE + n];
    int t = threadIdx.x;             // 0..191
    short4v* dst = (short4v*)(hC + (size_t)gn * ND);
    if (f32) {
        const float4* src = (const float4*)((const float*)emb + (size_t)id * ND);
        float4 v = src[t];
        short4v o; o.x = f2bs(v.x); o.y = f2bs(v.y); o.z = f2bs(v.z); o.w = f2bs(v.w);
        dst[t] = o;
    } else {
        dst[t] = ((const short4v*)((const bf16*)emb + (size_t)id * ND))[t];
    }
}

// x_out[n] = h[n] + sum_{e in CSR(n)} h[src_e]; 8-B vector loads, fp32 accum
__global__ __launch_bounds__(192) void gnn_aggregate_kernel(const bf16* __restrict__ hC,
                                                            const int* __restrict__ indptr,
                                                            const int* __restrict__ csr_src,
                                                            bf16* __restrict__ xC, int g0) {
    int gn = blockIdx.x;
    int gl = gn >> 11, n = gn & 2047;
    int g = g0 + gl;
    int beg = indptr[g * (NNODE + 1) + n];
    int end = indptr[g * (NNODE + 1) + n + 1];
    const short4v* hg = (const short4v*)(hC + (size_t)gl * NNODE * ND);  // row = 192 vecs
    const int* cs = csr_src + (size_t)g * NEDGE;
    int t = threadIdx.x;             // 0..191
    short4v v = hg[(size_t)n * 192 + t];
    float a0 = bs2f(v.x), a1 = bs2f(v.y), a2 = bs2f(v.z), a3 = bs2f(v.w);
    for (int e = beg; e < end; ++e) {
        int s = cs[e];
        short4v w = hg[(size_t)s * 192 + t];
        a0 += bs2f(w.x); a1 += bs2f(w.y); a2 += bs2f(w.z); a3 += bs2f(w.w);
    }
    short4v o; o.x = f2bs(a0); o.y = f2bs(a1); o.z = f2bs(a2); o.w = f2bs(a3);
    ((short4v*)(xC + (size_t)gn * ND))[t] = o;
}

// one block per (batch value, graph-in-chunk); sorted batch -> binary search; writes mean
__global__ __launch_bounds__(192) void readout_kernel(const bf16* __restrict__ hC,
                                                      const int* __restrict__ batch0,
                                                      const int* __restrict__ batch1,
                                                      float* __restrict__ pooled, int g0) {
    int gl = blockIdx.y;
    int g = g0 + gl;
    int b = blockIdx.x;
    const int* bp = (g < NK) ? (batch0 + (size_t)g * NNODE)
                             : (batch1 + (size_t)(g - NK) * NNODE);
    int lo = 0, hi = NNODE;
    while (lo < hi) { int mid = (lo + hi) >> 1; if (bp[mid] < b) lo = mid + 1; else hi = mid; }
    int start = lo;
    hi = NNODE;
    while (lo < hi) { int mid = (lo + hi) >> 1; if (bp[mid] < b + 1) lo = mid + 1; else hi = mid; }
    int end = lo;
    int t = threadIdx.x;             // 0..191
    const short4v* hg = (const short4v*)(hC + (size_t)gl * NNODE * ND);
    float a0 = 0.f, a1 = 0.f, a2 = 0.f, a3 = 0.f;
    for (int n = start; n < end; ++n) {
        short4v w = hg[(size_t)n * 192 + t];
        a0 += bs2f(w.x); a1 += bs2f(w.y); a2 += bs2f(w.z); a3 += bs2f(w.w);
    }
    float inv = 1.f / (float)max(end - start, 1);
    float4 o; o.x = a0 * inv; o.y = a1 * inv; o.z = a2 * inv; o.w = a3 * inv;
    ((float4*)(pooled + ((size_t)g * NB + b) * ND))[t] = o;
}

// ---------------- GEMM TN, double-buffered LDS, 1 barrier/iter ----------------
// C[M][N] = act(A[M][K] @ B[K][N] + bias[N]), BT = B^T [N][K] bf16, bias fp32.
__global__ __launch_bounds__(256) void gemm_tn(const bf16* __restrict__ A,
                                               const bf16* __restrict__ BT,
                                               const float* __restrict__ bias,
                                               void* __restrict__ C,
                                               int M, int K, int N,
                                               int act, int outF32) {
    __shared__ bf16 lA[2][128][32];
    __shared__ bf16 lB[2][128][32];
    int nTilesN = N >> 7;
    int bcol = blockIdx.x % nTilesN;
    int brow = blockIdx.x / nTilesN;
    int t = threadIdx.x;
    int wave = t >> 6, lane = t & 63;
    int wr = wave >> 1, wc = wave & 1;
    int l15 = lane & 15, quad = lane >> 4;
    const int row0 = brow << 7, col0 = bcol << 7;
    const int sr0 = t >> 2, sk0 = (t & 3) * 8;   // staging: LDS addr = 16*t -> conflict-free
    const bf16* Ab = A + (size_t)(row0 + sr0) * K + sk0;
    const bf16* Bb = BT + (size_t)(col0 + sr0) * K + sk0;
    const size_t rstride = (size_t)64 * K;

    // preload tile 0 into LDS buffer 0
    uint4 a0 = *(const uint4*)(Ab);
    uint4 a1 = *(const uint4*)(Ab + rstride);
    uint4 b0 = *(const uint4*)(Bb);
    uint4 b1 = *(const uint4*)(Bb + rstride);
    *(uint4*)&lA[0][sr0][sk0]      = a0;
    *(uint4*)&lA[0][sr0 + 64][sk0] = a1;
    *(uint4*)&lB[0][sr0][sk0]      = b0;
    *(uint4*)&lB[0][sr0 + 64][sk0] = b1;

    floatx4 acc[4][4] = {};
    int cur = 0;
    for (int k0 = 0; k0 < K; k0 += 32) {
        __syncthreads();             // lds[cur] ready; readers of lds[cur^1] done
        bool more = (k0 + 32) < K;
        if (more) {                  // issue next-tile loads early (overlap with MFMA)
            a0 = *(const uint4*)(Ab + k0 + 32);
            a1 = *(const uint4*)(Ab + rstride + k0 + 32);
            b0 = *(const uint4*)(Bb + k0 + 32);
            b1 = *(const uint4*)(Bb + rstride + k0 + 32);
        }
        short8 afr[4], bfr[4];
        #pragma unroll
        for (int i = 0; i < 4; ++i)
            afr[i] = *reinterpret_cast<const short8*>(&lA[cur][wr * 64 + i * 16 + l15][quad * 8]);
        #pragma unroll
        for (int j = 0; j < 4; ++j)
            bfr[j] = *reinterpret_cast<const short8*>(&lB[cur][wc * 64 + j * 16 + l15][quad * 8]);
        #pragma unroll
        for (int i = 0; i < 4; ++i)
            #pragma unroll
            for (int j = 0; j < 4; ++j)
                acc[i][j] = __builtin_amdgcn_mfma_f32_16x16x32_bf16(afr[i], bfr[j], acc[i][j], 0, 0, 0);
        if (more) {
            *(uint4*)&lA[cur ^ 1][sr0][sk0]      = a0;
            *(uint4*)&lA[cur ^ 1][sr0 + 64][sk0] = a1;
            *(uint4*)&lB[cur ^ 1][sr0][sk0]      = b0;
            *(uint4*)&lB[cur ^ 1][sr0 + 64][sk0] = b1;
        }
        cur ^= 1;
    }
    // epilogue: D[row=4*quad+r][col=l15] per 16x16 tile (verified m89/m91 layout)
    #pragma unroll
    for (int i = 0; i < 4; ++i) {
        int rbase = row0 + wr * 64 + i * 16 + quad * 4;
        #pragma unroll
        for (int j = 0; j < 4; ++j) {
            int c = col0 + wc * 64 + j * 16 + l15;
            float bv = bias[c];
            #pragma unroll
            for (int r = 0; r < 4; ++r) {
                float v = acc[i][j][r] + bv;
                if (act == 1) v = fmaxf(v, 0.f);
                else if (act == 2) {
                    float x = v;
                    float u = 1.5957691216057308f * (x + 0.044715f * x * x * x);
                    v = x / (1.f + __expf(-u));   // == 0.5x(1+tanh(u/2))
                }
                size_t idx = (size_t)(rbase + r) * N + c;
                if (outF32) ((float*)C)[idx] = v;
                else        ((bf16*)C)[idx] = f2b(v);
            }
        }
    }
}

// ---------------- LayerNorm helpers ----------------
__device__ __forceinline__ void block_ln_768(float (&x)[3], int t,
                                             const void* __restrict__ s,
                                             const void* __restrict__ b,
                                             size_t sOff, bool f32,
                                             float (&y)[3], float* red) {
    float loc = x[0] + x[1] + x[2];
    red[t] = loc; __syncthreads();
    for (int off = 128; off > 0; off >>= 1) {
        if (t < off) red[t] += red[t + off];
        __syncthreads();
    }
    float mean = red[0] * (1.f / 768.f);
    __syncthreads();
    float vs = 0.f;
    #pragma unroll
    for (int e = 0; e < 3; ++e) { float d = x[e] - mean; vs += d * d; }
    red[t] = vs; __syncthreads();
    for (int off = 128; off > 0; off >>= 1) {
        if (t < off) red[t] += red[t + off];
        __syncthreads();
    }
    float var = red[0] * (1.f / 768.f);
    __syncthreads();
    float inv = rsqrtf(var + 1e-12f);
    #pragma unroll
    for (int e = 0; e < 3; ++e) {
        int d = t + e * 256;
        y[e] = (x[e] - mean) * inv * ldf(s, sOff + d, f32) + ldf(b, sOff + d, f32);
    }
}

__global__ __launch_bounds__(256) void combine_embed_ln_kernel(
    const void* __restrict__ raw, const float* __restrict__ pooled,
    const int* __restrict__ role_ids, const int* __restrict__ pos_ids, const int* __restrict__ hop_ids,
    const void* __restrict__ role_emb, const void* __restrict__ pos_emb, const void* __restrict__ hop_emb,
    const void* __restrict__ lns, const void* __restrict__ lnb,
    float* __restrict__ hT, bf16* __restrict__ hbf,
    const int* __restrict__ flag) {
    bool f32 = flag[0] != 0;
    __shared__ float red[256];
    int token = blockIdx.x;          // b*NK + k
    int b = token >> 5, k = token & 31;
    int t = threadIdx.x;
    int rid = role_ids[b * NK + k];
    int pid = pos_ids[b * NK + k];
    int hid = hop_ids[b * NK + k];
    float x[3], y[3];
    #pragma unroll
    for (int e = 0; e < 3; ++e) {
        int d = t + e * 256;
        float p0 = pooled[((size_t)k * NB + b) * ND + d];
        float p1 = pooled[((size_t)(NK + k) * NB + b) * ND + d];
        x[e] = ldf(raw, (size_t)token * ND + d, f32) + p0 + p1
             + ldf(role_emb, (size_t)rid * ND + d, f32)
             + ldf(pos_emb, (size_t)pid * ND + d, f32)
             + ldf(hop_emb, (size_t)hid * ND + d, f32);
    }
    block_ln_768(x, t, lns, lnb, 0, f32, y, red);
    #pragma unroll
    for (int e = 0; e < 3; ++e) {
        int d = t + e * 256;
        hT[(size_t)token * ND + d] = y[e];
        hbf[(size_t)token * ND + d] = f2b(y[e]);
    }
}

__global__ __launch_bounds__(256) void add_ln_kernel(float* __restrict__ hT,
                                                     const float* __restrict__ addv,
                                                     const void* __restrict__ lns,
                                                     const void* __restrict__ lnb,
                                                     unsigned long long sOff,
                                                     void* __restrict__ outp, int extOut,
                                                     const int* __restrict__ flag) {
    bool f32 = flag[0] != 0;
    __shared__ float red[256];
    int token = blockIdx.x;
    int t = threadIdx.x;
    float x[3], y[3];
    #pragma unroll
    for (int e = 0; e < 3; ++e) {
        int d = t + e * 256;
        x[e] = hT[(size_t)token * ND + d] + addv[(size_t)token * ND + d];
    }
    block_ln_768(x, t, lns, lnb, sOff, f32, y, red);
    #pragma unroll
    for (int e = 0; e < 3; ++e) {
        int d = t + e * 256;
        size_t idx = (size_t)token * ND + d;
        hT[idx] = y[e];
        if (extOut && f32) ((float*)outp)[idx] = y[e];
        else               ((bf16*)outp)[idx] = f2b(y[e]);
    }
}

// ---------------- attention (per (b,head) 32x32), qkv fused [M][2304] ----------------
__global__ __launch_bounds__(256) void attn_kernel(const bf16* __restrict__ qkv,
                                                   bf16* __restrict__ ctx) {
    int blk = blockIdx.x;            // b*NHH + h
    int b = blk / NHH, h = blk % NHH;
    __shared__ float lq[NK][DHH], lk[NK][DHH], lv[NK][DHH];
    __shared__ float ls[NK][NK];
    int t = threadIdx.x;
    for (int i = t; i < NK * DHH; i += 256) {
        int tok = i >> 6, d = i & 63;
        size_t base = ((size_t)(b * NK + tok)) * (3 * ND) + h * DHH + d;
        lq[tok][d] = b2f(qkv[base]);
        lk[tok][d] = b2f(qkv[base + ND]);
        lv[tok][d] = b2f(qkv[base + 2 * ND]);
    }
    __syncthreads();
    const float scale = 0.125f;      // 1/sqrt(64)
    for (int i = t; i < NK * NK; i += 256) {
        int qi = i >> 5, kj = i & 31;
        float s = 0.f;
        #pragma unroll
        for (int d = 0; d < DHH; ++d) s += lq[qi][d] * lk[kj][d];
        ls[qi][kj] = s * scale;
    }
    __syncthreads();
    if (t < NK) {
        float m = -1e30f;
        for (int j = 0; j < NK; ++j) m = fmaxf(m, ls[t][j]);
        float sum = 0.f;
        for (int j = 0; j < NK; ++j) { float e = expf(ls[t][j] - m); ls[t][j] = e; sum += e; }
        float inv = 1.f / sum;
        for (int j = 0; j < NK; ++j) ls[t][j] *= inv;
    }
    __syncthreads();
    for (int i = t; i < NK * DHH; i += 256) {
        int qi = i >> 6, d = i & 63;
        float s = 0.f;
        #pragma unroll
        for (int j = 0; j < NK; ++j) s += ls[qi][j] * lv[j][d];
        ctx[((size_t)(b * NK + qi)) * ND + h * DHH + d] = f2b(s);
    }
}

// ---------------- launch ----------------
extern "C" void kernel_launch(void* const* d_in, const int* in_sizes, int n_in,
                              void* d_out, int out_size, void* d_ws, size_t ws_size,
                              hipStream_t stream) {
    const void* raw      = d_in[0];
    const int*  x0       = (const int*)d_in[1];
    const int*  edge0    = (const int*)d_in[2];
    const int*  batch0   = (const int*)d_in[3];
    const int*  x1       = (const int*)d_in[4];
    const int*  edge1    = (const int*)d_in[5];
    const int*  batch1   = (const int*)d_in[6];
    const int*  role_ids = (const int*)d_in[7];
    const int*  pos_ids  = (const int*)d_in[8];
    const int*  hop_ids  = (const int*)d_in[9];
    const void* amino    = d_in[10];
    const void* gnnW     = d_in[11];
    const void* gnnb     = d_in[12];
    const void* role_emb = d_in[13];
    const void* pos_emb  = d_in[14];
    const void* hop_emb  = d_in[15];
    const void* eln_s    = d_in[16];
    const void* eln_b    = d_in[17];
    const void* Wq       = d_in[18];
    const void* bq       = d_in[19];
    const void* Wk       = d_in[20];
    const void* bk       = d_in[21];
    const void* Wv       = d_in[22];
    const void* bv       = d_in[23];
    const void* Wo       = d_in[24];
    const void* bo       = d_in[25];
    const void* ln1_s    = d_in[26];
    const void* ln1_b    = d_in[27];
    const void* W1       = d_in[28];
    const void* b1       = d_in[29];
    const void* W2       = d_in[30];
    const void* b2       = d_in[31];
    const void* ln2_s    = d_in[32];
    const void* ln2_b    = d_in[33];

    char* ws = (char*)d_ws;
    size_t off = 0;
    auto alloc = [&](size_t bytes) -> void* {
        void* p = ws + off;
        off = (off + bytes + 255) & ~(size_t)255;
        return p;
    };
    int*   dflag   = (int*)alloc(256);
    float* pooled  = (float*)alloc((size_t)NG * NB * ND * 4);          // 6.29 MB
    int*   indptr  = (int*)alloc((size_t)NG * (NNODE + 1) * 4);        // 524 KB
    int*   csr_src = (int*)alloc((size_t)NG * NEDGE * 4);              // 4.19 MB
    int*   degcur  = (int*)alloc((size_t)NG * NNODE * 4);              // 524 KB
    bf16*  gnnT    = (bf16*)alloc((size_t)2 * ND * ND * 2);            // 2.36 MB
    bf16*  qkvT    = (bf16*)alloc((size_t)3 * ND * ND * 2);            // 3.54 MB (per-layer reuse)
    bf16*  oT      = (bf16*)alloc((size_t)ND * ND * 2);                // 1.18 MB
    bf16*  w1T     = (bf16*)alloc((size_t)ND * NFF * 2);               // 4.72 MB
    bf16*  w2T     = (bf16*)alloc((size_t)NFF * ND * 2);               // 4.72 MB
    float* biasPk  = (float*)alloc((size_t)(1536 + LTR * 6912) * 4);   // 117 KB

    // choose GNN chunk size by available workspace (graph-capture safe: ws_size constant)
    const size_t perG  = (size_t)NNODE * ND * 2;                       // 3.15 MB per graph buf
    const size_t bigTR = 21 * 1024 * 1024;                             // transformer view bound
    int gc = 8;
    for (int cand = 32; cand >= 8; cand >>= 1) {
        size_t bigGNN = 2 * (size_t)cand * perG;
        size_t need = off + (bigGNN > bigTR ? bigGNN : bigTR) + (1 << 20);
        if (need <= ws_size) { gc = cand; break; }
    }
    char* bigbase = (char*)alloc(2 * (size_t)gc * perG > bigTR ? 2 * (size_t)gc * perG : bigTR);
    bf16* hC = (bf16*)bigbase;
    bf16* xC = (bf16*)(bigbase + (size_t)gc * perG);
    size_t toff = 0;
    auto talloc = [&](size_t bytes) -> void* {
        void* p = bigbase + toff;
        toff = (toff + bytes + 255) & ~(size_t)255;
        return p;
    };
    float* hT    = (float*)talloc((size_t)NB * NK * ND * 4);
    bf16*  hbf   = (bf16*)talloc((size_t)NB * NK * ND * 2);
    bf16*  qkvb  = (bf16*)talloc((size_t)NB * NK * 3 * ND * 2);
    bf16*  ctxb  = (bf16*)talloc((size_t)NB * NK * ND * 2);
    float* resid = (float*)talloc((size_t)NB * NK * ND * 4);
    bf16*  ffbuf = (bf16*)talloc((size_t)NB * NK * NFF * 2);

    auto gemm = [&](const bf16* A, const bf16* BT, const float* bias, void* C,
                    int M, int K, int N, int act, int outF32) {
        int blocks = (M >> 7) * (N >> 7);
        gemm_tn<<<blocks, 256, 0, stream>>>(A, BT, bias, C, M, K, N, act, outF32);
    };

    // ---- dtype detection (precedes all external-input readers) ----
    detect_dtype_kernel<<<1, 64, 0, stream>>>(eln_s, dflag);

    // ---- weight/bias preconversion ----
    convert_gnn_kernel<<<288, 256, 0, stream>>>(gnnW, gnnT, dflag);
    pack_bias_kernel<<<(1536 + LTR * 6912 + 255) / 256, 256, 0, stream>>>(
        gnnb, bq, bk, bv, bo, b1, b2, biasPk, dflag);

    // ---- CSR build ----
    hipMemsetAsync(degcur, 0, (size_t)NG * NNODE * 4, stream);
    count_deg_kernel<<<NG * 64, 256, 0, stream>>>(edge0, edge1, degcur);
    scan_deg_kernel<<<NG, 256, 0, stream>>>(degcur, indptr);
    fill_csr_kernel<<<NG * 64, 256, 0, stream>>>(edge0, edge1, degcur, csr_src);

    // ---- GNN, chunked over graphs ----
    for (int g0 = 0; g0 < NG; g0 += gc) {
        gather_embed_kernel<<<gc * NNODE, 192, 0, stream>>>(x0, x1, amino, hC, g0, dflag);
        for (int l = 0; l < 2; ++l) {
            gnn_aggregate_kernel<<<gc * NNODE, 192, 0, stream>>>(hC, indptr, csr_src, xC, g0);
            gemm(xC, gnnT + (size_t)l * ND * ND, biasPk + l * ND, hC,
                 gc * NNODE, ND, ND, /*relu*/1, /*outF32*/0);
        }
        dim3 grid(NB, gc);
        readout_kernel<<<grid, 192, 0, stream>>>(hC, batch0, batch1, pooled, g0);
    }

    // ---- embeddings + LN ----
    combine_embed_ln_kernel<<<NB * NK, 256, 0, stream>>>(
        raw, pooled, role_ids, pos_ids, hop_ids,
        role_emb, pos_emb, hop_emb, eln_s, eln_b, hT, hbf, dflag);

    // ---- transformer ----
    const int M = NB * NK;
    for (int l = 0; l < LTR; ++l) {
        convert_layer_kernel<<<1728, 256, 0, stream>>>(Wq, Wk, Wv, Wo, W1, W2, l,
                                                       qkvT, oT, w1T, w2T, dflag);
        const float* lb = biasPk + 1536 + l * 6912;
        gemm(hbf, qkvT, lb, qkvb, M, ND, 3 * ND, 0, 0);                 // fused QKV
        attn_kernel<<<NB * NHH, 256, 0, stream>>>(qkvb, ctxb);
        gemm(ctxb, oT, lb + 2304, resid, M, ND, ND, 0, /*outF32*/1);
        add_ln_kernel<<<M, 256, 0, stream>>>(hT, resid, ln1_s, ln1_b,
                                             (unsigned long long)l * ND, hbf, 0, dflag);
        gemm(hbf, w1T, lb + 3072, ffbuf, M, ND, NFF, /*gelu*/2, 0);
        gemm(ffbuf, w2T, lb + 6144, resid, M, NFF, ND, 0, /*outF32*/1);
        int ext = (l == LTR - 1) ? 1 : 0;
        void* outb = ext ? d_out : (void*)hbf;
        add_ln_kernel<<<M, 256, 0, stream>>>(hT, resid, ln2_s, ln2_b,
                                             (unsigned long long)l * ND, outb, ext, dflag);
    }
}

// Round 7
// 1878.370 us; speedup vs baseline: 4.3118x; 1.1493x over previous
//
#include <hip/hip_runtime.h>
#include <hip/hip_bf16.h>
#include <math.h>

using bf16 = __hip_bfloat16;
typedef __attribute__((ext_vector_type(8))) short short8;
typedef __attribute__((ext_vector_type(4))) float floatx4;
typedef __attribute__((ext_vector_type(4))) short short4v;

#define NB   32      // batch
#define NK   32      // protein slots
#define NNODE 2048   // nodes per graph
#define NEDGE 16384  // edges per graph
#define ND   768     // hidden dim
#define NHH  12      // heads
#define DHH  64      // head dim
#define NFF  3072    // ff dim
#define NG   64      // graphs = 2*NK
#define LTR  4
#define VOCAB 25

static __device__ __forceinline__ float b2f(bf16 x) { return __bfloat162float(x); }
static __device__ __forceinline__ bf16 f2b(float x) { return __float2bfloat16(x); }
static __device__ __forceinline__ float bs2f(short s) {
    unsigned u = ((unsigned)(unsigned short)s) << 16;
    float f; __builtin_memcpy(&f, &u, 4); return f;
}
static __device__ __forceinline__ short f2bs(float x) {
    bf16 h = f2b(x); short s; __builtin_memcpy(&s, &h, 2); return s;
}

// dtype-flexible external load: f32 -> fp32 storage, else bf16 storage
static __device__ __forceinline__ float ldf(const void* p, size_t i, bool f32) {
    return f32 ? ((const float*)p)[i] : b2f(((const bf16*)p)[i]);
}

// ---------------- dtype detection ----------------
__global__ void detect_dtype_kernel(const void* __restrict__ eln_s, int* __restrict__ flag) {
    if (threadIdx.x == 0 && blockIdx.x == 0) {
        unsigned w = ((const unsigned*)eln_s)[0];
        flag[0] = (w == 0x3F800000u) ? 1 : 0;
    }
}

// ---------------- weight conversion: [R][Cn] (fp32/bf16) -> bf16 [Cn][R] ----------------
__device__ __forceinline__ void conv_tile(const void* __restrict__ src, size_t srcOff,
                                          bf16* __restrict__ dst, int R, int Cn,
                                          int tr, int tc, bool f32, int t,
                                          bf16 (*tile)[65]) {
    int r0 = tr * 64, c0 = tc * 64;
    #pragma unroll
    for (int p = 0; p < 16; ++p) {
        int idx = t + p * 256;
        int r = idx >> 6, c = idx & 63;
        tile[r][c] = f2b(ldf(src, srcOff + (size_t)(r0 + r) * Cn + c0 + c, f32));
    }
    __syncthreads();
    #pragma unroll
    for (int p = 0; p < 16; ++p) {
        int idx = t + p * 256;
        int c = idx >> 6, r = idx & 63;
        dst[(size_t)(c0 + c) * R + r0 + r] = tile[r][c];
    }
}

__global__ __launch_bounds__(256) void convert_gnn_kernel(const void* __restrict__ gnnW,
                                                          bf16* __restrict__ gnnT,
                                                          const int* __restrict__ flag) {
    __shared__ bf16 tile[64][65];
    bool f32 = flag[0] != 0;
    int bid = blockIdx.x;                 // 2 * 144
    int id = bid / 144, tl = bid % 144;
    conv_tile(gnnW, (size_t)id * 589824, gnnT + (size_t)id * 589824,
              768, 768, tl / 12, tl % 12, f32, threadIdx.x, tile);
}

__global__ __launch_bounds__(256) void convert_layer_kernel(
    const void* __restrict__ Wq, const void* __restrict__ Wk, const void* __restrict__ Wv,
    const void* __restrict__ Wo, const void* __restrict__ W1, const void* __restrict__ W2,
    int l, bf16* __restrict__ qkvT, bf16* __restrict__ oT,
    bf16* __restrict__ w1T, bf16* __restrict__ w2T, const int* __restrict__ flag) {
    __shared__ bf16 tile[64][65];
    bool f32 = flag[0] != 0;
    int bid = blockIdx.x, t = threadIdx.x;   // 1728 blocks
    if (bid < 432) {
        int m = bid / 144, tl = bid % 144;
        const void* src = (m == 0) ? Wq : ((m == 1) ? Wk : Wv);
        conv_tile(src, (size_t)l * 589824, qkvT + (size_t)m * 589824,
                  768, 768, tl / 12, tl % 12, f32, t, tile);
    } else if (bid < 576) {
        int tl = bid - 432;
        conv_tile(Wo, (size_t)l * 589824, oT, 768, 768, tl / 12, tl % 12, f32, t, tile);
    } else if (bid < 1152) {
        int tl = bid - 576;
        conv_tile(W1, (size_t)l * 768 * 3072, w1T, 768, 3072, tl / 48, tl % 48, f32, t, tile);
    } else {
        int tl = bid - 1152;
        conv_tile(W2, (size_t)l * 3072 * 768, w2T, 3072, 768, tl / 12, tl % 12, f32, t, tile);
    }
}

// pack biases fp32: [0,1536)=gnn, then per layer 6912: qkv(2304),o(768),b1(3072),b2(768)
__global__ __launch_bounds__(256) void pack_bias_kernel(
    const void* __restrict__ gnnb, const void* __restrict__ bq, const void* __restrict__ bk,
    const void* __restrict__ bv, const void* __restrict__ bo, const void* __restrict__ b1,
    const void* __restrict__ b2, float* __restrict__ out, const int* __restrict__ flag) {
    bool f32 = flag[0] != 0;
    int i = blockIdx.x * 256 + threadIdx.x;
    if (i >= 1536 + LTR * 6912) return;
    float v;
    if (i < 1536) v = ldf(gnnb, i, f32);
    else {
        int j = i - 1536, l = j / 6912, r = j % 6912;
        if      (r <  768) v = ldf(bq, l * 768 + r, f32);
        else if (r < 1536) v = ldf(bk, l * 768 + r - 768, f32);
        else if (r < 2304) v = ldf(bv, l * 768 + r - 1536, f32);
        else if (r < 3072) v = ldf(bo, l * 768 + r - 2304, f32);
        else if (r < 6144) v = ldf(b1, l * 3072 + r - 3072, f32);
        else               v = ldf(b2, l * 768 + r - 6144, f32);
    }
    out[i] = v;
}

// ---------------- E1 = emb @ W0  (25 x 768), stored bf16 ----------------
__global__ __launch_bounds__(192) void e1_kernel(const void* __restrict__ emb,
                                                 const bf16* __restrict__ w0T,
                                                 bf16* __restrict__ E1,
                                                 const int* __restrict__ flag) {
    bool f32 = flag[0] != 0;
    int v = blockIdx.x, t = threadIdx.x;      // v < 25; t covers 4 output cols
    float acc[4] = {0.f, 0.f, 0.f, 0.f};
    for (int k = 0; k < ND; k += 4) {
        float e0 = ldf(emb, (size_t)v * ND + k,     f32);
        float e1 = ldf(emb, (size_t)v * ND + k + 1, f32);
        float e2 = ldf(emb, (size_t)v * ND + k + 2, f32);
        float e3 = ldf(emb, (size_t)v * ND + k + 3, f32);
        #pragma unroll
        for (int j = 0; j < 4; ++j) {
            const short4v w = *(const short4v*)&w0T[(size_t)(t * 4 + j) * ND + k];
            acc[j] += e0 * bs2f(w.x) + e1 * bs2f(w.y) + e2 * bs2f(w.z) + e3 * bs2f(w.w);
        }
    }
    short4v o; o.x = f2bs(acc[0]); o.y = f2bs(acc[1]); o.z = f2bs(acc[2]); o.w = f2bs(acc[3]);
    ((short4v*)(E1 + (size_t)v * ND))[t] = o;
}

// ---------------- CSR build ----------------
__global__ __launch_bounds__(256) void count_deg_kernel(const int* __restrict__ edge0,
                                                        const int* __restrict__ edge1,
                                                        int* __restrict__ deg) {
    int gid = blockIdx.x;            // 64 graphs * 64 chunks
    int g = gid >> 6, chunk = gid & 63;
    const int* ep = (g < NK) ? (edge0 + (size_t)g * 2 * NEDGE)
                             : (edge1 + (size_t)(g - NK) * 2 * NEDGE);
    int e = chunk * 256 + threadIdx.x;
    int dst = ep[NEDGE + e];
    atomicAdd(&deg[g * NNODE + dst], 1);
}

__global__ __launch_bounds__(256) void scan_deg_kernel(int* __restrict__ deg,
                                                       int* __restrict__ indptr) {
    int g = blockIdx.x, t = threadIdx.x;
    __shared__ int sums[256];
    int loc[8]; int s = 0;
    #pragma unroll
    for (int i = 0; i < 8; ++i) { loc[i] = deg[g * NNODE + t * 8 + i]; s += loc[i]; }
    sums[t] = s; __syncthreads();
    for (int off = 1; off < 256; off <<= 1) {
        int v = (t >= off) ? sums[t - off] : 0;
        __syncthreads();
        sums[t] += v;
        __syncthreads();
    }
    int run = sums[t] - s;           // exclusive prefix
    #pragma unroll
    for (int i = 0; i < 8; ++i) {
        indptr[g * (NNODE + 1) + t * 8 + i] = run;
        deg[g * NNODE + t * 8 + i] = run;   // becomes cursor
        run += loc[i];
    }
    if (t == 255) indptr[g * (NNODE + 1) + NNODE] = run;
}

__global__ __launch_bounds__(256) void fill_csr_kernel(const int* __restrict__ edge0,
                                                       const int* __restrict__ edge1,
                                                       int* __restrict__ cursor,
                                                       int* __restrict__ csr_src) {
    int gid = blockIdx.x;
    int g = gid >> 6, chunk = gid & 63;
    const int* ep = (g < NK) ? (edge0 + (size_t)g * 2 * NEDGE)
                             : (edge1 + (size_t)(g - NK) * 2 * NEDGE);
    int e = chunk * 256 + threadIdx.x;
    int src = ep[e];
    int dst = ep[NEDGE + e];
    int p = atomicAdd(&cursor[g * NNODE + dst], 1);
    csr_src[(size_t)g * NEDGE + p] = src;
}

// ---------------- GNN layer 1, fused: h1[n] = relu(E1[x[n]] + sum E1[x[src]] + b0) ----------------
__global__ __launch_bounds__(192) void gnn_layer1_kernel(const int* __restrict__ x0,
                                                         const int* __restrict__ x1,
                                                         const bf16* __restrict__ E1,
                                                         const float* __restrict__ b0,
                                                         const int* __restrict__ indptr,
                                                         const int* __restrict__ csr_src,
                                                         bf16* __restrict__ hC, int g0) {
    int gn = blockIdx.x;
    int gl = gn >> 11, n = gn & 2047;
    int g = g0 + gl;
    const int* xg = (g < NK) ? (x0 + (size_t)g * NNODE) : (x1 + (size_t)(g - NK) * NNODE);
    int beg = indptr[g * (NNODE + 1) + n];
    int end = indptr[g * (NNODE + 1) + n + 1];
    const int* cs = csr_src + (size_t)g * NEDGE;
    int t = threadIdx.x;             // 0..191, 4 dims/lane
    const short4v* E = (const short4v*)E1;   // row = 192 vecs
    short4v v = E[(size_t)xg[n] * 192 + t];
    float a0 = bs2f(v.x), a1 = bs2f(v.y), a2 = bs2f(v.z), a3 = bs2f(v.w);
    for (int e = beg; e < end; ++e) {
        int s = cs[e];
        short4v w = E[(size_t)xg[s] * 192 + t];
        a0 += bs2f(w.x); a1 += bs2f(w.y); a2 += bs2f(w.z); a3 += bs2f(w.w);
    }
    float4 bb = ((const float4*)b0)[t];
    short4v o;
    o.x = f2bs(fmaxf(a0 + bb.x, 0.f));
    o.y = f2bs(fmaxf(a1 + bb.y, 0.f));
    o.z = f2bs(fmaxf(a2 + bb.z, 0.f));
    o.w = f2bs(fmaxf(a3 + bb.w, 0.f));
    ((short4v*)(hC + (size_t)gn * ND))[t] = o;
}

// x_out[n] = h[n] + sum_{e in CSR(n)} h[src_e]; 8-B vector loads, fp32 accum
__global__ __launch_bounds__(192) void gnn_aggregate_kernel(const bf16* __restrict__ hC,
                                                            const int* __restrict__ indptr,
                                                            const int* __restrict__ csr_src,
                                                            bf16* __restrict__ xC, int g0) {
    int gn = blockIdx.x;
    int gl = gn >> 11, n = gn & 2047;
    int g = g0 + gl;
    int beg = indptr[g * (NNODE + 1) + n];
    int end = indptr[g * (NNODE + 1) + n + 1];
    const short4v* hg = (const short4v*)(hC + (size_t)gl * NNODE * ND);  // row = 192 vecs
    const int* cs = csr_src + (size_t)g * NEDGE;
    int t = threadIdx.x;             // 0..191
    short4v v = hg[(size_t)n * 192 + t];
    float a0 = bs2f(v.x), a1 = bs2f(v.y), a2 = bs2f(v.z), a3 = bs2f(v.w);
    for (int e = beg; e < end; ++e) {
        int s = cs[e];
        short4v w = hg[(size_t)s * 192 + t];
        a0 += bs2f(w.x); a1 += bs2f(w.y); a2 += bs2f(w.z); a3 += bs2f(w.w);
    }
    short4v o; o.x = f2bs(a0); o.y = f2bs(a1); o.z = f2bs(a2); o.w = f2bs(a3);
    ((short4v*)(xC + (size_t)gn * ND))[t] = o;
}

// one block per (batch value, graph-in-chunk); sorted batch -> binary search; writes mean
__global__ __launch_bounds__(192) void readout_kernel(const bf16* __restrict__ hC,
                                                      const int* __restrict__ batch0,
                                                      const int* __restrict__ batch1,
                                                      float* __restrict__ pooled, int g0) {
    int gl = blockIdx.y;
    int g = g0 + gl;
    int b = blockIdx.x;
    const int* bp = (g < NK) ? (batch0 + (size_t)g * NNODE)
                             : (batch1 + (size_t)(g - NK) * NNODE);
    int lo = 0, hi = NNODE;
    while (lo < hi) { int mid = (lo + hi) >> 1; if (bp[mid] < b) lo = mid + 1; else hi = mid; }
    int start = lo;
    hi = NNODE;
    while (lo < hi) { int mid = (lo + hi) >> 1; if (bp[mid] < b + 1) lo = mid + 1; else hi = mid; }
    int end = lo;
    int t = threadIdx.x;             // 0..191
    const short4v* hg = (const short4v*)(hC + (size_t)gl * NNODE * ND);
    float a0 = 0.f, a1 = 0.f, a2 = 0.f, a3 = 0.f;
    for (int n = start; n < end; ++n) {
        short4v w = hg[(size_t)n * 192 + t];
        a0 += bs2f(w.x); a1 += bs2f(w.y); a2 += bs2f(w.z); a3 += bs2f(w.w);
    }
    float inv = 1.f / (float)max(end - start, 1);
    float4 o; o.x = a0 * inv; o.y = a1 * inv; o.z = a2 * inv; o.w = a3 * inv;
    ((float4*)(pooled + ((size_t)g * NB + b) * ND))[t] = o;
}

// ---------------- GEMM TN, double-buffered LDS, XCD-swizzled blocks ----------------
// C[M][N] = act(A[M][K] @ B[K][N] + bias[N]), BT = B^T [N][K] bf16, bias fp32.
__global__ __launch_bounds__(256) void gemm_tn(const bf16* __restrict__ A,
                                               const bf16* __restrict__ BT,
                                               const float* __restrict__ bias,
                                               void* __restrict__ C,
                                               int M, int K, int N,
                                               int act, int outF32) {
    __shared__ bf16 lA[2][128][32];
    __shared__ bf16 lB[2][128][32];
    int nTilesN = N >> 7, nTilesM = M >> 7;
    int brow, bcol;
    if ((nTilesM & 7) == 0) {
        // XCD-aware: all col-tiles of one row-group share blockIdx%8 -> same XCD L2
        int xcd = blockIdx.x & 7, j = blockIdx.x >> 3;
        brow = (j / nTilesN) * 8 + xcd;
        bcol = j % nTilesN;
    } else {
        bcol = blockIdx.x % nTilesN;
        brow = blockIdx.x / nTilesN;
    }
    int t = threadIdx.x;
    int wave = t >> 6, lane = t & 63;
    int wr = wave >> 1, wc = wave & 1;
    int l15 = lane & 15, quad = lane >> 4;
    const int row0 = brow << 7, col0 = bcol << 7;
    const int sr0 = t >> 2, sk0 = (t & 3) * 8;   // staging: LDS addr = 16*t -> conflict-free
    const bf16* Ab = A + (size_t)(row0 + sr0) * K + sk0;
    const bf16* Bb = BT + (size_t)(col0 + sr0) * K + sk0;
    const size_t rstride = (size_t)64 * K;

    // preload tile 0 into LDS buffer 0
    uint4 a0 = *(const uint4*)(Ab);
    uint4 a1 = *(const uint4*)(Ab + rstride);
    uint4 b0 = *(const uint4*)(Bb);
    uint4 b1 = *(const uint4*)(Bb + rstride);
    *(uint4*)&lA[0][sr0][sk0]      = a0;
    *(uint4*)&lA[0][sr0 + 64][sk0] = a1;
    *(uint4*)&lB[0][sr0][sk0]      = b0;
    *(uint4*)&lB[0][sr0 + 64][sk0] = b1;

    floatx4 acc[4][4] = {};
    int cur = 0;
    for (int k0 = 0; k0 < K; k0 += 32) {
        __syncthreads();             // lds[cur] ready; readers of lds[cur^1] done
        bool more = (k0 + 32) < K;
        if (more) {                  // issue next-tile loads early (overlap with MFMA)
            a0 = *(const uint4*)(Ab + k0 + 32);
            a1 = *(const uint4*)(Ab + rstride + k0 + 32);
            b0 = *(const uint4*)(Bb + k0 + 32);
            b1 = *(const uint4*)(Bb + rstride + k0 + 32);
        }
        short8 afr[4], bfr[4];
        #pragma unroll
        for (int i = 0; i < 4; ++i)
            afr[i] = *reinterpret_cast<const short8*>(&lA[cur][wr * 64 + i * 16 + l15][quad * 8]);
        #pragma unroll
        for (int j = 0; j < 4; ++j)
            bfr[j] = *reinterpret_cast<const short8*>(&lB[cur][wc * 64 + j * 16 + l15][quad * 8]);
        #pragma unroll
        for (int i = 0; i < 4; ++i)
            #pragma unroll
            for (int j = 0; j < 4; ++j)
                acc[i][j] = __builtin_amdgcn_mfma_f32_16x16x32_bf16(afr[i], bfr[j], acc[i][j], 0, 0, 0);
        if (more) {
            *(uint4*)&lA[cur ^ 1][sr0][sk0]      = a0;
            *(uint4*)&lA[cur ^ 1][sr0 + 64][sk0] = a1;
            *(uint4*)&lB[cur ^ 1][sr0][sk0]      = b0;
            *(uint4*)&lB[cur ^ 1][sr0 + 64][sk0] = b1;
        }
        cur ^= 1;
    }
    // epilogue: D[row=4*quad+r][col=l15] per 16x16 tile (verified m89/m91 layout)
    #pragma unroll
    for (int i = 0; i < 4; ++i) {
        int rbase = row0 + wr * 64 + i * 16 + quad * 4;
        #pragma unroll
        for (int j = 0; j < 4; ++j) {
            int c = col0 + wc * 64 + j * 16 + l15;
            float bv = bias[c];
            #pragma unroll
            for (int r = 0; r < 4; ++r) {
                float v = acc[i][j][r] + bv;
                if (act == 1) v = fmaxf(v, 0.f);
                else if (act == 2) {
                    float x = v;
                    float u = 1.5957691216057308f * (x + 0.044715f * x * x * x);
                    v = x / (1.f + __expf(-u));   // == 0.5x(1+tanh(u/2))
                }
                size_t idx = (size_t)(rbase + r) * N + c;
                if (outF32) ((float*)C)[idx] = v;
                else        ((bf16*)C)[idx] = f2b(v);
            }
        }
    }
}

// ---------------- LayerNorm helpers ----------------
__device__ __forceinline__ void block_ln_768(float (&x)[3], int t,
                                             const void* __restrict__ s,
                                             const void* __restrict__ b,
                                             size_t sOff, bool f32,
                                             float (&y)[3], float* red) {
    float loc = x[0] + x[1] + x[2];
    red[t] = loc; __syncthreads();
    for (int off = 128; off > 0; off >>= 1) {
        if (t < off) red[t] += red[t + off];
        __syncthreads();
    }
    float mean = red[0] * (1.f / 768.f);
    __syncthreads();
    float vs = 0.f;
    #pragma unroll
    for (int e = 0; e < 3; ++e) { float d = x[e] - mean; vs += d * d; }
    red[t] = vs; __syncthreads();
    for (int off = 128; off > 0; off >>= 1) {
        if (t < off) red[t] += red[t + off];
        __syncthreads();
    }
    float var = red[0] * (1.f / 768.f);
    __syncthreads();
    float inv = rsqrtf(var + 1e-12f);
    #pragma unroll
    for (int e = 0; e < 3; ++e) {
        int d = t + e * 256;
        y[e] = (x[e] - mean) * inv * ldf(s, sOff + d, f32) + ldf(b, sOff + d, f32);
    }
}

__global__ __launch_bounds__(256) void combine_embed_ln_kernel(
    const void* __restrict__ raw, const float* __restrict__ pooled,
    const int* __restrict__ role_ids, const int* __restrict__ pos_ids, const int* __restrict__ hop_ids,
    const void* __restrict__ role_emb, const void* __restrict__ pos_emb, const void* __restrict__ hop_emb,
    const void* __restrict__ lns, const void* __restrict__ lnb,
    float* __restrict__ hT, bf16* __restrict__ hbf,
    const int* __restrict__ flag) {
    bool f32 = flag[0] != 0;
    __shared__ float red[256];
    int token = blockIdx.x;          // b*NK + k
    int b = token >> 5, k = token & 31;
    int t = threadIdx.x;
    int rid = role_ids[b * NK + k];
    int pid = pos_ids[b * NK + k];
    int hid = hop_ids[b * NK + k];
    float x[3], y[3];
    #pragma unroll
    for (int e = 0; e < 3; ++e) {
        int d = t + e * 256;
        float p0 = pooled[((size_t)k * NB + b) * ND + d];
        float p1 = pooled[((size_t)(NK + k) * NB + b) * ND + d];
        x[e] = ldf(raw, (size_t)token * ND + d, f32) + p0 + p1
             + ldf(role_emb, (size_t)rid * ND + d, f32)
             + ldf(pos_emb, (size_t)pid * ND + d, f32)
             + ldf(hop_emb, (size_t)hid * ND + d, f32);
    }
    block_ln_768(x, t, lns, lnb, 0, f32, y, red);
    #pragma unroll
    for (int e = 0; e < 3; ++e) {
        int d = t + e * 256;
        hT[(size_t)token * ND + d] = y[e];
        hbf[(size_t)token * ND + d] = f2b(y[e]);
    }
}

__global__ __launch_bounds__(256) void add_ln_kernel(float* __restrict__ hT,
                                                     const float* __restrict__ addv,
                                                     const void* __restrict__ lns,
                                                     const void* __restrict__ lnb,
                                                     unsigned long long sOff,
                                                     void* __restrict__ outp, int extOut,
                                                     const int* __restrict__ flag) {
    bool f32 = flag[0] != 0;
    __shared__ float red[256];
    int token = blockIdx.x;
    int t = threadIdx.x;
    float x[3], y[3];
    #pragma unroll
    for (int e = 0; e < 3; ++e) {
        int d = t + e * 256;
        x[e] = hT[(size_t)token * ND + d] + addv[(size_t)token * ND + d];
    }
    block_ln_768(x, t, lns, lnb, sOff, f32, y, red);
    #pragma unroll
    for (int e = 0; e < 3; ++e) {
        int d = t + e * 256;
        size_t idx = (size_t)token * ND + d;
        hT[idx] = y[e];
        if (extOut && f32) ((float*)outp)[idx] = y[e];
        else               ((bf16*)outp)[idx] = f2b(y[e]);
    }
}

// ---------------- attention (per (b,head) 32x32), qkv fused [M][2304] ----------------
__global__ __launch_bounds__(256) void attn_kernel(const bf16* __restrict__ qkv,
                                                   bf16* __restrict__ ctx) {
    int blk = blockIdx.x;            // b*NHH + h
    int b = blk / NHH, h = blk % NHH;
    __shared__ float lq[NK][DHH], lk[NK][DHH], lv[NK][DHH];
    __shared__ float ls[NK][NK];
    int t = threadIdx.x;
    for (int i = t; i < NK * DHH; i += 256) {
        int tok = i >> 6, d = i & 63;
        size_t base = ((size_t)(b * NK + tok)) * (3 * ND) + h * DHH + d;
        lq[tok][d] = b2f(qkv[base]);
        lk[tok][d] = b2f(qkv[base + ND]);
        lv[tok][d] = b2f(qkv[base + 2 * ND]);
    }
    __syncthreads();
    const float scale = 0.125f;      // 1/sqrt(64)
    for (int i = t; i < NK * NK; i += 256) {
        int qi = i >> 5, kj = i & 31;
        float s = 0.f;
        #pragma unroll
        for (int d = 0; d < DHH; ++d) s += lq[qi][d] * lk[kj][d];
        ls[qi][kj] = s * scale;
    }
    __syncthreads();
    if (t < NK) {
        float m = -1e30f;
        for (int j = 0; j < NK; ++j) m = fmaxf(m, ls[t][j]);
        float sum = 0.f;
        for (int j = 0; j < NK; ++j) { float e = expf(ls[t][j] - m); ls[t][j] = e; sum += e; }
        float inv = 1.f / sum;
        for (int j = 0; j < NK; ++j) ls[t][j] *= inv;
    }
    __syncthreads();
    for (int i = t; i < NK * DHH; i += 256) {
        int qi = i >> 6, d = i & 63;
        float s = 0.f;
        #pragma unroll
        for (int j = 0; j < NK; ++j) s += ls[qi][j] * lv[j][d];
        ctx[((size_t)(b * NK + qi)) * ND + h * DHH + d] = f2b(s);
    }
}

// ---------------- launch ----------------
extern "C" void kernel_launch(void* const* d_in, const int* in_sizes, int n_in,
                              void* d_out, int out_size, void* d_ws, size_t ws_size,
                              hipStream_t stream) {
    const void* raw      = d_in[0];
    const int*  x0       = (const int*)d_in[1];
    const int*  edge0    = (const int*)d_in[2];
    const int*  batch0   = (const int*)d_in[3];
    const int*  x1       = (const int*)d_in[4];
    const int*  edge1    = (const int*)d_in[5];
    const int*  batch1   = (const int*)d_in[6];
    const int*  role_ids = (const int*)d_in[7];
    const int*  pos_ids  = (const int*)d_in[8];
    const int*  hop_ids  = (const int*)d_in[9];
    const void* amino    = d_in[10];
    const void* gnnW     = d_in[11];
    const void* gnnb     = d_in[12];
    const void* role_emb = d_in[13];
    const void* pos_emb  = d_in[14];
    const void* hop_emb  = d_in[15];
    const void* eln_s    = d_in[16];
    const void* eln_b    = d_in[17];
    const void* Wq       = d_in[18];
    const void* bq       = d_in[19];
    const void* Wk       = d_in[20];
    const void* bk       = d_in[21];
    const void* Wv       = d_in[22];
    const void* bv       = d_in[23];
    const void* Wo       = d_in[24];
    const void* bo       = d_in[25];
    const void* ln1_s    = d_in[26];
    const void* ln1_b    = d_in[27];
    const void* W1       = d_in[28];
    const void* b1       = d_in[29];
    const void* W2       = d_in[30];
    const void* b2       = d_in[31];
    const void* ln2_s    = d_in[32];
    const void* ln2_b    = d_in[33];

    char* ws = (char*)d_ws;
    size_t off = 0;
    auto alloc = [&](size_t bytes) -> void* {
        void* p = ws + off;
        off = (off + bytes + 255) & ~(size_t)255;
        return p;
    };
    int*   dflag   = (int*)alloc(256);
    float* pooled  = (float*)alloc((size_t)NG * NB * ND * 4);          // 6.29 MB
    int*   indptr  = (int*)alloc((size_t)NG * (NNODE + 1) * 4);        // 524 KB
    int*   csr_src = (int*)alloc((size_t)NG * NEDGE * 4);              // 4.19 MB
    int*   degcur  = (int*)alloc((size_t)NG * NNODE * 4);              // 524 KB
    bf16*  gnnT    = (bf16*)alloc((size_t)2 * ND * ND * 2);            // 2.36 MB
    bf16*  E1      = (bf16*)alloc((size_t)VOCAB * ND * 2);             // 38 KB
    bf16*  qkvT    = (bf16*)alloc((size_t)3 * ND * ND * 2);            // 3.54 MB (per-layer reuse)
    bf16*  oT      = (bf16*)alloc((size_t)ND * ND * 2);                // 1.18 MB
    bf16*  w1T     = (bf16*)alloc((size_t)ND * NFF * 2);               // 4.72 MB
    bf16*  w2T     = (bf16*)alloc((size_t)NFF * ND * 2);               // 4.72 MB
    float* biasPk  = (float*)alloc((size_t)(1536 + LTR * 6912) * 4);   // 117 KB

    // choose GNN chunk size by available workspace (ws_size constant across calls)
    const size_t perG  = (size_t)NNODE * ND * 2;                       // 3.15 MB per graph buf
    const size_t bigTR = 21 * 1024 * 1024;                             // transformer view bound
    int gc = 8;
    for (int cand = 32; cand >= 8; cand >>= 1) {
        size_t bigGNN = 2 * (size_t)cand * perG;
        size_t need = off + (bigGNN > bigTR ? bigGNN : bigTR) + (1 << 20);
        if (need <= ws_size) { gc = cand; break; }
    }
    char* bigbase = (char*)alloc(2 * (size_t)gc * perG > bigTR ? 2 * (size_t)gc * perG : bigTR);
    bf16* hC = (bf16*)bigbase;
    bf16* xC = (bf16*)(bigbase + (size_t)gc * perG);
    size_t toff = 0;
    auto talloc = [&](size_t bytes) -> void* {
        void* p = bigbase + toff;
        toff = (toff + bytes + 255) & ~(size_t)255;
        return p;
    };
    float* hT    = (float*)talloc((size_t)NB * NK * ND * 4);
    bf16*  hbf   = (bf16*)talloc((size_t)NB * NK * ND * 2);
    bf16*  qkvb  = (bf16*)talloc((size_t)NB * NK * 3 * ND * 2);
    bf16*  ctxb  = (bf16*)talloc((size_t)NB * NK * ND * 2);
    float* resid = (float*)talloc((size_t)NB * NK * ND * 4);
    bf16*  ffbuf = (bf16*)talloc((size_t)NB * NK * NFF * 2);

    auto gemm = [&](const bf16* A, const bf16* BT, const float* bias, void* C,
                    int M, int K, int N, int act, int outF32) {
        int blocks = (M >> 7) * (N >> 7);
        gemm_tn<<<blocks, 256, 0, stream>>>(A, BT, bias, C, M, K, N, act, outF32);
    };

    // ---- dtype detection (precedes all external-input readers) ----
    detect_dtype_kernel<<<1, 64, 0, stream>>>(eln_s, dflag);

    // ---- weight/bias preconversion ----
    convert_gnn_kernel<<<288, 256, 0, stream>>>(gnnW, gnnT, dflag);
    pack_bias_kernel<<<(1536 + LTR * 6912 + 255) / 256, 256, 0, stream>>>(
        gnnb, bq, bk, bv, bo, b1, b2, biasPk, dflag);
    // E1 = emb @ W0 (25 x 768): layer-1 GEMM collapses to a table lookup
    e1_kernel<<<VOCAB, 192, 0, stream>>>(amino, gnnT, E1, dflag);

    // ---- CSR build ----
    hipMemsetAsync(degcur, 0, (size_t)NG * NNODE * 4, stream);
    count_deg_kernel<<<NG * 64, 256, 0, stream>>>(edge0, edge1, degcur);
    scan_deg_kernel<<<NG, 256, 0, stream>>>(degcur, indptr);
    fill_csr_kernel<<<NG * 64, 256, 0, stream>>>(edge0, edge1, degcur, csr_src);

    // ---- GNN, chunked over graphs; layer 1 fully fused via E1 ----
    for (int g0 = 0; g0 < NG; g0 += gc) {
        gnn_layer1_kernel<<<gc * NNODE, 192, 0, stream>>>(x0, x1, E1, biasPk,
                                                          indptr, csr_src, hC, g0);
        gnn_aggregate_kernel<<<gc * NNODE, 192, 0, stream>>>(hC, indptr, csr_src, xC, g0);
        gemm(xC, gnnT + (size_t)ND * ND, biasPk + ND, hC,
             gc * NNODE, ND, ND, /*relu*/1, /*outF32*/0);
        dim3 grid(NB, gc);
        readout_kernel<<<grid, 192, 0, stream>>>(hC, batch0, batch1, pooled, g0);
    }

    // ---- embeddings + LN ----
    combine_embed_ln_kernel<<<NB * NK, 256, 0, stream>>>(
        raw, pooled, role_ids, pos_ids, hop_ids,
        role_emb, pos_emb, hop_emb, eln_s, eln_b, hT, hbf, dflag);

    // ---- transformer ----
    const int M = NB * NK;
    for (int l = 0; l < LTR; ++l) {
        convert_layer_kernel<<<1728, 256, 0, stream>>>(Wq, Wk, Wv, Wo, W1, W2, l,
                                                       qkvT, oT, w1T, w2T, dflag);
        const float* lb = biasPk + 1536 + l * 6912;
        gemm(hbf, qkvT, lb, qkvb, M, ND, 3 * ND, 0, 0);                 // fused QKV
        attn_kernel<<<NB * NHH, 256, 0, stream>>>(qkvb, ctxb);
        gemm(ctxb, oT, lb + 2304, resid, M, ND, ND, 0, /*outF32*/1);
        add_ln_kernel<<<M, 256, 0, stream>>>(hT, resid, ln1_s, ln1_b,
                                             (unsigned long long)l * ND, hbf, 0, dflag);
        gemm(hbf, w1T, lb + 3072, ffbuf, M, ND, NFF, /*gelu*/2, 0);
        gemm(ffbuf, w2T, lb + 6144, resid, M, NFF, ND, 0, /*outF32*/1);
        int ext = (l == LTR - 1) ? 1 : 0;
        void* outb = ext ? d_out : (void*)hbf;
        add_ln_kernel<<<M, 256, 0, stream>>>(hT, resid, ln2_s, ln2_b,
                                             (unsigned long long)l * ND, outb, ext, dflag);
    }
}

// Round 8
// 1682.452 us; speedup vs baseline: 4.8139x; 1.1164x over previous
//
#include <hip/hip_runtime.h>
#include <hip/hip_bf16.h>
#include <math.h>

using bf16 = __hip_bfloat16;
typedef __attribute__((ext_vector_type(8))) short short8;
typedef __attribute__((ext_vector_type(4))) float floatx4;
typedef __attribute__((ext_vector_type(4))) short short4v;

#define NB   32      // batch
#define NK   32      // protein slots
#define NNODE 2048   // nodes per graph
#define NEDGE 16384  // edges per graph
#define ND   768     // hidden dim
#define NHH  12      // heads
#define DHH  64      // head dim
#define NFF  3072    // ff dim
#define NG   64      // graphs = 2*NK
#define LTR  4
#define VOCAB 25

static __device__ __forceinline__ float b2f(bf16 x) { return __bfloat162float(x); }
static __device__ __forceinline__ bf16 f2b(float x) { return __float2bfloat16(x); }
static __device__ __forceinline__ float bs2f(short s) {
    unsigned u = ((unsigned)(unsigned short)s) << 16;
    float f; __builtin_memcpy(&f, &u, 4); return f;
}
static __device__ __forceinline__ short f2bs(float x) {
    bf16 h = f2b(x); short s; __builtin_memcpy(&s, &h, 2); return s;
}

// async global->LDS, 16B per lane; LDS dest = wave-uniform base + lane*16
static __device__ __forceinline__ void load_lds16(const bf16* g, bf16* l) {
    __builtin_amdgcn_global_load_lds((const __attribute__((address_space(1))) void*)g,
                                     (__attribute__((address_space(3))) void*)l, 16, 0, 0);
}

// dtype-flexible external load: f32 -> fp32 storage, else bf16 storage
static __device__ __forceinline__ float ldf(const void* p, size_t i, bool f32) {
    return f32 ? ((const float*)p)[i] : b2f(((const bf16*)p)[i]);
}

// ---------------- dtype detection ----------------
__global__ void detect_dtype_kernel(const void* __restrict__ eln_s, int* __restrict__ flag) {
    if (threadIdx.x == 0 && blockIdx.x == 0) {
        unsigned w = ((const unsigned*)eln_s)[0];
        flag[0] = (w == 0x3F800000u) ? 1 : 0;
    }
}

// ---------------- weight conversion: [R][Cn] (fp32/bf16) -> bf16 [Cn][R] ----------------
__device__ __forceinline__ void conv_tile(const void* __restrict__ src, size_t srcOff,
                                          bf16* __restrict__ dst, int R, int Cn,
                                          int tr, int tc, bool f32, int t,
                                          bf16 (*tile)[65]) {
    int r0 = tr * 64, c0 = tc * 64;
    #pragma unroll
    for (int p = 0; p < 16; ++p) {
        int idx = t + p * 256;
        int r = idx >> 6, c = idx & 63;
        tile[r][c] = f2b(ldf(src, srcOff + (size_t)(r0 + r) * Cn + c0 + c, f32));
    }
    __syncthreads();
    #pragma unroll
    for (int p = 0; p < 16; ++p) {
        int idx = t + p * 256;
        int c = idx >> 6, r = idx & 63;
        dst[(size_t)(c0 + c) * R + r0 + r] = tile[r][c];
    }
}

__global__ __launch_bounds__(256) void convert_gnn_kernel(const void* __restrict__ gnnW,
                                                          bf16* __restrict__ gnnT,
                                                          const int* __restrict__ flag) {
    __shared__ bf16 tile[64][65];
    bool f32 = flag[0] != 0;
    int bid = blockIdx.x;                 // 2 * 144
    int id = bid / 144, tl = bid % 144;
    conv_tile(gnnW, (size_t)id * 589824, gnnT + (size_t)id * 589824,
              768, 768, tl / 12, tl % 12, f32, threadIdx.x, tile);
}

__global__ __launch_bounds__(256) void convert_layer_kernel(
    const void* __restrict__ Wq, const void* __restrict__ Wk, const void* __restrict__ Wv,
    const void* __restrict__ Wo, const void* __restrict__ W1, const void* __restrict__ W2,
    int l, bf16* __restrict__ qkvT, bf16* __restrict__ oT,
    bf16* __restrict__ w1T, bf16* __restrict__ w2T, const int* __restrict__ flag) {
    __shared__ bf16 tile[64][65];
    bool f32 = flag[0] != 0;
    int bid = blockIdx.x, t = threadIdx.x;   // 1728 blocks
    if (bid < 432) {
        int m = bid / 144, tl = bid % 144;
        const void* src = (m == 0) ? Wq : ((m == 1) ? Wk : Wv);
        conv_tile(src, (size_t)l * 589824, qkvT + (size_t)m * 589824,
                  768, 768, tl / 12, tl % 12, f32, t, tile);
    } else if (bid < 576) {
        int tl = bid - 432;
        conv_tile(Wo, (size_t)l * 589824, oT, 768, 768, tl / 12, tl % 12, f32, t, tile);
    } else if (bid < 1152) {
        int tl = bid - 576;
        conv_tile(W1, (size_t)l * 768 * 3072, w1T, 768, 3072, tl / 48, tl % 48, f32, t, tile);
    } else {
        int tl = bid - 1152;
        conv_tile(W2, (size_t)l * 3072 * 768, w2T, 3072, 768, tl / 12, tl % 12, f32, t, tile);
    }
}

// pack biases fp32: [0,1536)=gnn, then per layer 6912: qkv(2304),o(768),b1(3072),b2(768)
__global__ __launch_bounds__(256) void pack_bias_kernel(
    const void* __restrict__ gnnb, const void* __restrict__ bq, const void* __restrict__ bk,
    const void* __restrict__ bv, const void* __restrict__ bo, const void* __restrict__ b1,
    const void* __restrict__ b2, float* __restrict__ out, const int* __restrict__ flag) {
    bool f32 = flag[0] != 0;
    int i = blockIdx.x * 256 + threadIdx.x;
    if (i >= 1536 + LTR * 6912) return;
    float v;
    if (i < 1536) v = ldf(gnnb, i, f32);
    else {
        int j = i - 1536, l = j / 6912, r = j % 6912;
        if      (r <  768) v = ldf(bq, l * 768 + r, f32);
        else if (r < 1536) v = ldf(bk, l * 768 + r - 768, f32);
        else if (r < 2304) v = ldf(bv, l * 768 + r - 1536, f32);
        else if (r < 3072) v = ldf(bo, l * 768 + r - 2304, f32);
        else if (r < 6144) v = ldf(b1, l * 3072 + r - 3072, f32);
        else               v = ldf(b2, l * 768 + r - 6144, f32);
    }
    out[i] = v;
}

// ---------------- E1 = emb @ W0  (25 x 768), stored bf16 ----------------
__global__ __launch_bounds__(192) void e1_kernel(const void* __restrict__ emb,
                                                 const bf16* __restrict__ w0T,
                                                 bf16* __restrict__ E1,
                                                 const int* __restrict__ flag) {
    bool f32 = flag[0] != 0;
    int v = blockIdx.x, t = threadIdx.x;      // v < 25; t covers 4 output cols
    float acc[4] = {0.f, 0.f, 0.f, 0.f};
    for (int k = 0; k < ND; k += 4) {
        float e0 = ldf(emb, (size_t)v * ND + k,     f32);
        float e1 = ldf(emb, (size_t)v * ND + k + 1, f32);
        float e2 = ldf(emb, (size_t)v * ND + k + 2, f32);
        float e3 = ldf(emb, (size_t)v * ND + k + 3, f32);
        #pragma unroll
        for (int j = 0; j < 4; ++j) {
            const short4v w = *(const short4v*)&w0T[(size_t)(t * 4 + j) * ND + k];
            acc[j] += e0 * bs2f(w.x) + e1 * bs2f(w.y) + e2 * bs2f(w.z) + e3 * bs2f(w.w);
        }
    }
    short4v o; o.x = f2bs(acc[0]); o.y = f2bs(acc[1]); o.z = f2bs(acc[2]); o.w = f2bs(acc[3]);
    ((short4v*)(E1 + (size_t)v * ND))[t] = o;
}

// ---------------- CSR build ----------------
__global__ __launch_bounds__(256) void count_deg_kernel(const int* __restrict__ edge0,
                                                        const int* __restrict__ edge1,
                                                        int* __restrict__ deg) {
    int gid = blockIdx.x;            // 64 graphs * 64 chunks
    int g = gid >> 6, chunk = gid & 63;
    const int* ep = (g < NK) ? (edge0 + (size_t)g * 2 * NEDGE)
                             : (edge1 + (size_t)(g - NK) * 2 * NEDGE);
    int e = chunk * 256 + threadIdx.x;
    int dst = ep[NEDGE + e];
    atomicAdd(&deg[g * NNODE + dst], 1);
}

__global__ __launch_bounds__(256) void scan_deg_kernel(int* __restrict__ deg,
                                                       int* __restrict__ indptr) {
    int g = blockIdx.x, t = threadIdx.x;
    __shared__ int sums[256];
    int loc[8]; int s = 0;
    #pragma unroll
    for (int i = 0; i < 8; ++i) { loc[i] = deg[g * NNODE + t * 8 + i]; s += loc[i]; }
    sums[t] = s; __syncthreads();
    for (int off = 1; off < 256; off <<= 1) {
        int v = (t >= off) ? sums[t - off] : 0;
        __syncthreads();
        sums[t] += v;
        __syncthreads();
    }
    int run = sums[t] - s;           // exclusive prefix
    #pragma unroll
    for (int i = 0; i < 8; ++i) {
        indptr[g * (NNODE + 1) + t * 8 + i] = run;
        deg[g * NNODE + t * 8 + i] = run;   // becomes cursor
        run += loc[i];
    }
    if (t == 255) indptr[g * (NNODE + 1) + NNODE] = run;
}

__global__ __launch_bounds__(256) void fill_csr_kernel(const int* __restrict__ edge0,
                                                       const int* __restrict__ edge1,
                                                       int* __restrict__ cursor,
                                                       int* __restrict__ csr_src) {
    int gid = blockIdx.x;
    int g = gid >> 6, chunk = gid & 63;
    const int* ep = (g < NK) ? (edge0 + (size_t)g * 2 * NEDGE)
                             : (edge1 + (size_t)(g - NK) * 2 * NEDGE);
    int e = chunk * 256 + threadIdx.x;
    int src = ep[e];
    int dst = ep[NEDGE + e];
    int p = atomicAdd(&cursor[g * NNODE + dst], 1);
    csr_src[(size_t)g * NEDGE + p] = src;
}

// XCD-local decode: all blocks of graph gl share blockIdx % 8 -> same XCD L2
static __device__ __forceinline__ void node_block_decode(int id, int& gl, int& n) {
    int r = id & 7, q = id >> 3;
    gl = r + 8 * (q >> 11);          // requires gc % 8 == 0
    n = q & 2047;
}

// ---------------- GNN layer 1, fused: h1[n] = relu(E1[x[n]] + sum E1[x[src]] + b0) ----------------
__global__ __launch_bounds__(192) void gnn_layer1_kernel(const int* __restrict__ x0,
                                                         const int* __restrict__ x1,
                                                         const bf16* __restrict__ E1,
                                                         const float* __restrict__ b0,
                                                         const int* __restrict__ indptr,
                                                         const int* __restrict__ csr_src,
                                                         bf16* __restrict__ hC, int g0) {
    int gl, n; node_block_decode(blockIdx.x, gl, n);
    int g = g0 + gl;
    const int* xg = (g < NK) ? (x0 + (size_t)g * NNODE) : (x1 + (size_t)(g - NK) * NNODE);
    int beg = indptr[g * (NNODE + 1) + n];
    int end = indptr[g * (NNODE + 1) + n + 1];
    const int* cs = csr_src + (size_t)g * NEDGE;
    int t = threadIdx.x;             // 0..191, 4 dims/lane
    const short4v* E = (const short4v*)E1;   // row = 192 vecs
    short4v v = E[(size_t)xg[n] * 192 + t];
    float a0 = bs2f(v.x), a1 = bs2f(v.y), a2 = bs2f(v.z), a3 = bs2f(v.w);
    for (int e = beg; e < end; ++e) {
        int s = cs[e];
        short4v w = E[(size_t)xg[s] * 192 + t];
        a0 += bs2f(w.x); a1 += bs2f(w.y); a2 += bs2f(w.z); a3 += bs2f(w.w);
    }
    float4 bb = ((const float4*)b0)[t];
    short4v o;
    o.x = f2bs(fmaxf(a0 + bb.x, 0.f));
    o.y = f2bs(fmaxf(a1 + bb.y, 0.f));
    o.z = f2bs(fmaxf(a2 + bb.z, 0.f));
    o.w = f2bs(fmaxf(a3 + bb.w, 0.f));
    ((short4v*)(hC + ((size_t)gl * NNODE + n) * ND))[t] = o;
}

// x_out[n] = h[n] + sum_{e in CSR(n)} h[src_e]; 8-B vector loads, fp32 accum
__global__ __launch_bounds__(192) void gnn_aggregate_kernel(const bf16* __restrict__ hC,
                                                            const int* __restrict__ indptr,
                                                            const int* __restrict__ csr_src,
                                                            bf16* __restrict__ xC, int g0) {
    int gl, n; node_block_decode(blockIdx.x, gl, n);
    int g = g0 + gl;
    int beg = indptr[g * (NNODE + 1) + n];
    int end = indptr[g * (NNODE + 1) + n + 1];
    const short4v* hg = (const short4v*)(hC + (size_t)gl * NNODE * ND);  // row = 192 vecs
    const int* cs = csr_src + (size_t)g * NEDGE;
    int t = threadIdx.x;             // 0..191
    short4v v = hg[(size_t)n * 192 + t];
    float a0 = bs2f(v.x), a1 = bs2f(v.y), a2 = bs2f(v.z), a3 = bs2f(v.w);
    for (int e = beg; e < end; ++e) {
        int s = cs[e];
        short4v w = hg[(size_t)s * 192 + t];
        a0 += bs2f(w.x); a1 += bs2f(w.y); a2 += bs2f(w.z); a3 += bs2f(w.w);
    }
    short4v o; o.x = f2bs(a0); o.y = f2bs(a1); o.z = f2bs(a2); o.w = f2bs(a3);
    ((short4v*)(xC + ((size_t)gl * NNODE + n) * ND))[t] = o;
}

// one block per (batch value, graph-in-chunk); sorted batch -> binary search; writes mean
__global__ __launch_bounds__(192) void readout_kernel(const bf16* __restrict__ hC,
                                                      const int* __restrict__ batch0,
                                                      const int* __restrict__ batch1,
                                                      float* __restrict__ pooled, int g0) {
    int id = blockIdx.x;
    int r = id & 7, q = id >> 3;
    int gl = r + 8 * (q >> 5);       // graph -> same XCD as its node blocks
    int b = q & 31;
    int g = g0 + gl;
    const int* bp = (g < NK) ? (batch0 + (size_t)g * NNODE)
                             : (batch1 + (size_t)(g - NK) * NNODE);
    int lo = 0, hi = NNODE;
    while (lo < hi) { int mid = (lo + hi) >> 1; if (bp[mid] < b) lo = mid + 1; else hi = mid; }
    int start = lo;
    hi = NNODE;
    while (lo < hi) { int mid = (lo + hi) >> 1; if (bp[mid] < b + 1) lo = mid + 1; else hi = mid; }
    int end = lo;
    int t = threadIdx.x;             // 0..191
    const short4v* hg = (const short4v*)(hC + (size_t)gl * NNODE * ND);
    float a0 = 0.f, a1 = 0.f, a2 = 0.f, a3 = 0.f;
    for (int n = start; n < end; ++n) {
        short4v w = hg[(size_t)n * 192 + t];
        a0 += bs2f(w.x); a1 += bs2f(w.y); a2 += bs2f(w.z); a3 += bs2f(w.w);
    }
    float inv = 1.f / (float)max(end - start, 1);
    float4 o; o.x = a0 * inv; o.y = a1 * inv; o.z = a2 * inv; o.w = a3 * inv;
    ((float4*)(pooled + ((size_t)g * NB + b) * ND))[t] = o;
}

// ---------------- GEMM TN: async global_load_lds staging, dbuf LDS, XCD swizzle ----------------
// C[M][N] = act(A[M][K] @ B[K][N] + bias[N]), BT = B^T [N][K] bf16, bias fp32.
__global__ __launch_bounds__(256) void gemm_tn(const bf16* __restrict__ A,
                                               const bf16* __restrict__ BT,
                                               const float* __restrict__ bias,
                                               void* __restrict__ C,
                                               int M, int K, int N,
                                               int act, int outF32) {
    __shared__ bf16 lA[2][128][32];
    __shared__ bf16 lB[2][128][32];
    int nTilesN = N >> 7, nTilesM = M >> 7;
    int brow, bcol;
    if ((nTilesM & 7) == 0) {
        int xcd = blockIdx.x & 7, j = blockIdx.x >> 3;
        brow = (j / nTilesN) * 8 + xcd;
        bcol = j % nTilesN;
    } else {
        bcol = blockIdx.x % nTilesN;
        brow = blockIdx.x / nTilesN;
    }
    int t = threadIdx.x;
    int wave = t >> 6, lane = t & 63;
    int wr = wave >> 1, wc = wave & 1;
    int l15 = lane & 15, quad = lane >> 4;
    const int row0 = brow << 7, col0 = bcol << 7;
    // staging map: LDS addr = 16*t bytes -> per wave: base + lane*16 (global_load_lds layout)
    const int sr0 = t >> 2, sk0 = (t & 3) * 8;
    const bf16* Ab = A + (size_t)(row0 + sr0) * K + sk0;
    const bf16* Bb = BT + (size_t)(col0 + sr0) * K + sk0;
    const size_t rstride = (size_t)64 * K;

    // async preload tile 0 -> buffer 0
    load_lds16(Ab,           &lA[0][sr0][sk0]);
    load_lds16(Ab + rstride, &lA[0][sr0 + 64][sk0]);
    load_lds16(Bb,           &lB[0][sr0][sk0]);
    load_lds16(Bb + rstride, &lB[0][sr0 + 64][sk0]);

    floatx4 acc[4][4] = {};
    int cur = 0;
    for (int k0 = 0; k0 < K; k0 += 32) {
        __syncthreads();             // vmcnt(0) drain: lds[cur] ready; prior reads of lds[cur^1] done
        if (k0 + 32 < K) {           // async prefetch next tile into the other buffer
            load_lds16(Ab + k0 + 32,           &lA[cur ^ 1][sr0][sk0]);
            load_lds16(Ab + rstride + k0 + 32, &lA[cur ^ 1][sr0 + 64][sk0]);
            load_lds16(Bb + k0 + 32,           &lB[cur ^ 1][sr0][sk0]);
            load_lds16(Bb + rstride + k0 + 32, &lB[cur ^ 1][sr0 + 64][sk0]);
        }
        short8 afr[4], bfr[4];
        #pragma unroll
        for (int i = 0; i < 4; ++i)
            afr[i] = *reinterpret_cast<const short8*>(&lA[cur][wr * 64 + i * 16 + l15][quad * 8]);
        #pragma unroll
        for (int j = 0; j < 4; ++j)
            bfr[j] = *reinterpret_cast<const short8*>(&lB[cur][wc * 64 + j * 16 + l15][quad * 8]);
        #pragma unroll
        for (int i = 0; i < 4; ++i)
            #pragma unroll
            for (int j = 0; j < 4; ++j)
                acc[i][j] = __builtin_amdgcn_mfma_f32_16x16x32_bf16(afr[i], bfr[j], acc[i][j], 0, 0, 0);
        cur ^= 1;
    }
    // epilogue: D[row=4*quad+r][col=l15] per 16x16 tile (verified m89/m91 layout)
    #pragma unroll
    for (int i = 0; i < 4; ++i) {
        int rbase = row0 + wr * 64 + i * 16 + quad * 4;
        #pragma unroll
        for (int j = 0; j < 4; ++j) {
            int c = col0 + wc * 64 + j * 16 + l15;
            float bv = bias[c];
            #pragma unroll
            for (int r = 0; r < 4; ++r) {
                float v = acc[i][j][r] + bv;
                if (act == 1) v = fmaxf(v, 0.f);
                else if (act == 2) {
                    float x = v;
                    float u = 1.5957691216057308f * (x + 0.044715f * x * x * x);
                    v = x / (1.f + __expf(-u));   // == 0.5x(1+tanh(u/2))
                }
                size_t idx = (size_t)(rbase + r) * N + c;
                if (outF32) ((float*)C)[idx] = v;
                else        ((bf16*)C)[idx] = f2b(v);
            }
        }
    }
}

// ---------------- LayerNorm helpers ----------------
__device__ __forceinline__ void block_ln_768(float (&x)[3], int t,
                                             const void* __restrict__ s,
                                             const void* __restrict__ b,
                                             size_t sOff, bool f32,
                                             float (&y)[3], float* red) {
    float loc = x[0] + x[1] + x[2];
    red[t] = loc; __syncthreads();
    for (int off = 128; off > 0; off >>= 1) {
        if (t < off) red[t] += red[t + off];
        __syncthreads();
    }
    float mean = red[0] * (1.f / 768.f);
    __syncthreads();
    float vs = 0.f;
    #pragma unroll
    for (int e = 0; e < 3; ++e) { float d = x[e] - mean; vs += d * d; }
    red[t] = vs; __syncthreads();
    for (int off = 128; off > 0; off >>= 1) {
        if (t < off) red[t] += red[t + off];
        __syncthreads();
    }
    float var = red[0] * (1.f / 768.f);
    __syncthreads();
    float inv = rsqrtf(var + 1e-12f);
    #pragma unroll
    for (int e = 0; e < 3; ++e) {
        int d = t + e * 256;
        y[e] = (x[e] - mean) * inv * ldf(s, sOff + d, f32) + ldf(b, sOff + d, f32);
    }
}

__global__ __launch_bounds__(256) void combine_embed_ln_kernel(
    const void* __restrict__ raw, const float* __restrict__ pooled,
    const int* __restrict__ role_ids, const int* __restrict__ pos_ids, const int* __restrict__ hop_ids,
    const void* __restrict__ role_emb, const void* __restrict__ pos_emb, const void* __restrict__ hop_emb,
    const void* __restrict__ lns, const void* __restrict__ lnb,
    float* __restrict__ hT, bf16* __restrict__ hbf,
    const int* __restrict__ flag) {
    bool f32 = flag[0] != 0;
    __shared__ float red[256];
    int token = blockIdx.x;          // b*NK + k
    int b = token >> 5, k = token & 31;
    int t = threadIdx.x;
    int rid = role_ids[b * NK + k];
    int pid = pos_ids[b * NK + k];
    int hid = hop_ids[b * NK + k];
    float x[3], y[3];
    #pragma unroll
    for (int e = 0; e < 3; ++e) {
        int d = t + e * 256;
        float p0 = pooled[((size_t)k * NB + b) * ND + d];
        float p1 = pooled[((size_t)(NK + k) * NB + b) * ND + d];
        x[e] = ldf(raw, (size_t)token * ND + d, f32) + p0 + p1
             + ldf(role_emb, (size_t)rid * ND + d, f32)
             + ldf(pos_emb, (size_t)pid * ND + d, f32)
             + ldf(hop_emb, (size_t)hid * ND + d, f32);
    }
    block_ln_768(x, t, lns, lnb, 0, f32, y, red);
    #pragma unroll
    for (int e = 0; e < 3; ++e) {
        int d = t + e * 256;
        hT[(size_t)token * ND + d] = y[e];
        hbf[(size_t)token * ND + d] = f2b(y[e]);
    }
}

__global__ __launch_bounds__(256) void add_ln_kernel(float* __restrict__ hT,
                                                     const float* __restrict__ addv,
                                                     const void* __restrict__ lns,
                                                     const void* __restrict__ lnb,
                                                     unsigned long long sOff,
                                                     void* __restrict__ outp, int extOut,
                                                     const int* __restrict__ flag) {
    bool f32 = flag[0] != 0;
    __shared__ float red[256];
    int token = blockIdx.x;
    int t = threadIdx.x;
    float x[3], y[3];
    #pragma unroll
    for (int e = 0; e < 3; ++e) {
        int d = t + e * 256;
        x[e] = hT[(size_t)token * ND + d] + addv[(size_t)token * ND + d];
    }
    block_ln_768(x, t, lns, lnb, sOff, f32, y, red);
    #pragma unroll
    for (int e = 0; e < 3; ++e) {
        int d = t + e * 256;
        size_t idx = (size_t)token * ND + d;
        hT[idx] = y[e];
        if (extOut && f32) ((float*)outp)[idx] = y[e];
        else               ((bf16*)outp)[idx] = f2b(y[e]);
    }
}

// ---------------- attention (per (b,head) 32x32), qkv fused [M][2304] ----------------
__global__ __launch_bounds__(256) void attn_kernel(const bf16* __restrict__ qkv,
                                                   bf16* __restrict__ ctx) {
    int blk = blockIdx.x;            // b*NHH + h
    int b = blk / NHH, h = blk % NHH;
    __shared__ float lq[NK][DHH], lk[NK][DHH], lv[NK][DHH];
    __shared__ float ls[NK][NK];
    int t = threadIdx.x;
    for (int i = t; i < NK * DHH; i += 256) {
        int tok = i >> 6, d = i & 63;
        size_t base = ((size_t)(b * NK + tok)) * (3 * ND) + h * DHH + d;
        lq[tok][d] = b2f(qkv[base]);
        lk[tok][d] = b2f(qkv[base + ND]);
        lv[tok][d] = b2f(qkv[base + 2 * ND]);
    }
    __syncthreads();
    const float scale = 0.125f;      // 1/sqrt(64)
    for (int i = t; i < NK * NK; i += 256) {
        int qi = i >> 5, kj = i & 31;
        float s = 0.f;
        #pragma unroll
        for (int d = 0; d < DHH; ++d) s += lq[qi][d] * lk[kj][d];
        ls[qi][kj] = s * scale;
    }
    __syncthreads();
    if (t < NK) {
        float m = -1e30f;
        for (int j = 0; j < NK; ++j) m = fmaxf(m, ls[t][j]);
        float sum = 0.f;
        for (int j = 0; j < NK; ++j) { float e = expf(ls[t][j] - m); ls[t][j] = e; sum += e; }
        float inv = 1.f / sum;
        for (int j = 0; j < NK; ++j) ls[t][j] *= inv;
    }
    __syncthreads();
    for (int i = t; i < NK * DHH; i += 256) {
        int qi = i >> 6, d = i & 63;
        float s = 0.f;
        #pragma unroll
        for (int j = 0; j < NK; ++j) s += ls[qi][j] * lv[j][d];
        ctx[((size_t)(b * NK + qi)) * ND + h * DHH + d] = f2b(s);
    }
}

// ---------------- launch ----------------
extern "C" void kernel_launch(void* const* d_in, const int* in_sizes, int n_in,
                              void* d_out, int out_size, void* d_ws, size_t ws_size,
                              hipStream_t stream) {
    const void* raw      = d_in[0];
    const int*  x0       = (const int*)d_in[1];
    const int*  edge0    = (const int*)d_in[2];
    const int*  batch0   = (const int*)d_in[3];
    const int*  x1       = (const int*)d_in[4];
    const int*  edge1    = (const int*)d_in[5];
    const int*  batch1   = (const int*)d_in[6];
    const int*  role_ids = (const int*)d_in[7];
    const int*  pos_ids  = (const int*)d_in[8];
    const int*  hop_ids  = (const int*)d_in[9];
    const void* amino    = d_in[10];
    const void* gnnW     = d_in[11];
    const void* gnnb     = d_in[12];
    const void* role_emb = d_in[13];
    const void* pos_emb  = d_in[14];
    const void* hop_emb  = d_in[15];
    const void* eln_s    = d_in[16];
    const void* eln_b    = d_in[17];
    const void* Wq       = d_in[18];
    const void* bq       = d_in[19];
    const void* Wk       = d_in[20];
    const void* bk       = d_in[21];
    const void* Wv       = d_in[22];
    const void* bv       = d_in[23];
    const void* Wo       = d_in[24];
    const void* bo       = d_in[25];
    const void* ln1_s    = d_in[26];
    const void* ln1_b    = d_in[27];
    const void* W1       = d_in[28];
    const void* b1       = d_in[29];
    const void* W2       = d_in[30];
    const void* b2       = d_in[31];
    const void* ln2_s    = d_in[32];
    const void* ln2_b    = d_in[33];

    char* ws = (char*)d_ws;
    size_t off = 0;
    auto alloc = [&](size_t bytes) -> void* {
        void* p = ws + off;
        off = (off + bytes + 255) & ~(size_t)255;
        return p;
    };
    int*   dflag   = (int*)alloc(256);
    float* pooled  = (float*)alloc((size_t)NG * NB * ND * 4);          // 6.29 MB
    int*   indptr  = (int*)alloc((size_t)NG * (NNODE + 1) * 4);        // 524 KB
    int*   csr_src = (int*)alloc((size_t)NG * NEDGE * 4);              // 4.19 MB
    int*   degcur  = (int*)alloc((size_t)NG * NNODE * 4);              // 524 KB
    bf16*  gnnT    = (bf16*)alloc((size_t)2 * ND * ND * 2);            // 2.36 MB
    bf16*  E1      = (bf16*)alloc((size_t)VOCAB * ND * 2);             // 38 KB
    bf16*  qkvT    = (bf16*)alloc((size_t)3 * ND * ND * 2);            // 3.54 MB (per-layer reuse)
    bf16*  oT      = (bf16*)alloc((size_t)ND * ND * 2);                // 1.18 MB
    bf16*  w1T     = (bf16*)alloc((size_t)ND * NFF * 2);               // 4.72 MB
    bf16*  w2T     = (bf16*)alloc((size_t)NFF * ND * 2);               // 4.72 MB
    float* biasPk  = (float*)alloc((size_t)(1536 + LTR * 6912) * 4);   // 117 KB

    // choose GNN chunk size by available workspace (ws_size constant across calls)
    const size_t perG  = (size_t)NNODE * ND * 2;                       // 3.15 MB per graph buf
    const size_t bigTR = 21 * 1024 * 1024;                             // transformer view bound
    int gc = 8;
    for (int cand = 32; cand >= 8; cand >>= 1) {
        size_t bigGNN = 2 * (size_t)cand * perG;
        size_t need = off + (bigGNN > bigTR ? bigGNN : bigTR) + (1 << 20);
        if (need <= ws_size) { gc = cand; break; }
    }
    char* bigbase = (char*)alloc(2 * (size_t)gc * perG > bigTR ? 2 * (size_t)gc * perG : bigTR);
    bf16* hC = (bf16*)bigbase;
    bf16* xC = (bf16*)(bigbase + (size_t)gc * perG);
    size_t toff = 0;
    auto talloc = [&](size_t bytes) -> void* {
        void* p = bigbase + toff;
        toff = (toff + bytes + 255) & ~(size_t)255;
        return p;
    };
    float* hT    = (float*)talloc((size_t)NB * NK * ND * 4);
    bf16*  hbf   = (bf16*)talloc((size_t)NB * NK * ND * 2);
    bf16*  qkvb  = (bf16*)talloc((size_t)NB * NK * 3 * ND * 2);
    bf16*  ctxb  = (bf16*)talloc((size_t)NB * NK * ND * 2);
    float* resid = (float*)talloc((size_t)NB * NK * ND * 4);
    bf16*  ffbuf = (bf16*)talloc((size_t)NB * NK * NFF * 2);

    auto gemm = [&](const bf16* A, const bf16* BT, const float* bias, void* C,
                    int M, int K, int N, int act, int outF32) {
        int blocks = (M >> 7) * (N >> 7);
        gemm_tn<<<blocks, 256, 0, stream>>>(A, BT, bias, C, M, K, N, act, outF32);
    };

    // ---- dtype detection (precedes all external-input readers) ----
    detect_dtype_kernel<<<1, 64, 0, stream>>>(eln_s, dflag);

    // ---- weight/bias preconversion ----
    convert_gnn_kernel<<<288, 256, 0, stream>>>(gnnW, gnnT, dflag);
    pack_bias_kernel<<<(1536 + LTR * 6912 + 255) / 256, 256, 0, stream>>>(
        gnnb, bq, bk, bv, bo, b1, b2, biasPk, dflag);
    // E1 = emb @ W0 (25 x 768): layer-1 GEMM collapses to a table lookup
    e1_kernel<<<VOCAB, 192, 0, stream>>>(amino, gnnT, E1, dflag);

    // ---- CSR build ----
    hipMemsetAsync(degcur, 0, (size_t)NG * NNODE * 4, stream);
    count_deg_kernel<<<NG * 64, 256, 0, stream>>>(edge0, edge1, degcur);
    scan_deg_kernel<<<NG, 256, 0, stream>>>(degcur, indptr);
    fill_csr_kernel<<<NG * 64, 256, 0, stream>>>(edge0, edge1, degcur, csr_src);

    // ---- GNN, chunked over graphs; layer 1 fully fused via E1 ----
    for (int g0 = 0; g0 < NG; g0 += gc) {
        gnn_layer1_kernel<<<gc * NNODE, 192, 0, stream>>>(x0, x1, E1, biasPk,
                                                          indptr, csr_src, hC, g0);
        gnn_aggregate_kernel<<<gc * NNODE, 192, 0, stream>>>(hC, indptr, csr_src, xC, g0);
        gemm(xC, gnnT + (size_t)ND * ND, biasPk + ND, hC,
             gc * NNODE, ND, ND, /*relu*/1, /*outF32*/0);
        readout_kernel<<<gc * NB, 192, 0, stream>>>(hC, batch0, batch1, pooled, g0);
    }

    // ---- embeddings + LN ----
    combine_embed_ln_kernel<<<NB * NK, 256, 0, stream>>>(
        raw, pooled, role_ids, pos_ids, hop_ids,
        role_emb, pos_emb, hop_emb, eln_s, eln_b, hT, hbf, dflag);

    // ---- transformer ----
    const int M = NB * NK;
    for (int l = 0; l < LTR; ++l) {
        convert_layer_kernel<<<1728, 256, 0, stream>>>(Wq, Wk, Wv, Wo, W1, W2, l,
                                                       qkvT, oT, w1T, w2T, dflag);
        const float* lb = biasPk + 1536 + l * 6912;
        gemm(hbf, qkvT, lb, qkvb, M, ND, 3 * ND, 0, 0);                 // fused QKV
        attn_kernel<<<NB * NHH, 256, 0, stream>>>(qkvb, ctxb);
        gemm(ctxb, oT, lb + 2304, resid, M, ND, ND, 0, /*outF32*/1);
        add_ln_kernel<<<M, 256, 0, stream>>>(hT, resid, ln1_s, ln1_b,
                                             (unsigned long long)l * ND, hbf, 0, dflag);
        gemm(hbf, w1T, lb + 3072, ffbuf, M, ND, NFF, /*gelu*/2, 0);
        gemm(ffbuf, w2T, lb + 6144, resid, M, NFF, ND, 0, /*outF32*/1);
        int ext = (l == LTR - 1) ? 1 : 0;
        void* outb = ext ? d_out : (void*)hbf;
        add_ln_kernel<<<M, 256, 0, stream>>>(hT, resid, ln2_s, ln2_b,
                                             (unsigned long long)l * ND, outb, ext, dflag);
    }
}